// Round 9
// baseline (2154841.797 us; speedup 1.0000x reference)
//
#include <hip/hip_runtime.h>
#include <hip/hip_bf16.h>
#include <cmath>

// L=128, B=256, H=256, C=17, Y=16, N_SUB=2
#define L_   128
#define B_   256
#define H_   256
#define C_   17
#define Y_   16
#define NSUB 254
#define NGRP 8           // groups (b-slabs of 32)
#define RNK  32          // ranks per group (8 h each)

typedef short bf16x8 __attribute__((ext_vector_type(8)));
typedef float f32x4  __attribute__((ext_vector_type(4)));
typedef unsigned int u32x2 __attribute__((ext_vector_type(2)));
typedef unsigned short u16;
typedef unsigned int   u32;

// ---- workspace byte offsets ------------------------------------------------
#define OFF_DXR  0u           // [254][256 b][20 c] f32              5,201,920
#define OFF_W2H  5201920u     // [32 r][10 mt][8 kt][64][8] u16      2,621,440
#define OFF_W2L  7823360u
#define OFF_W1H  10444800u    // [16 mtg][8 kt][64][8] u16             131,072
#define OFF_W1L  10575872u
#define OFF_DEH  10706944u    // [8 kt][64][8] u16                       8,192
#define OFF_DEL  10715136u
#define OFF_ZLH  10723328u    // zF LOCAL hi [2buf][8grp][16KB]        262,144
#define OFF_ZLL  10985472u
#define OFF_ZMH  11247616u    // zF MALL  hi                           262,144
#define OFF_ZML  11509760u
#define OFF_FLL  11771904u    // flgL u64[8 grp][32 rank]                2,048
#define OFF_FLM  11773952u    // flgM u64[8][32]                         2,048
#define OFF_ARR  11776000u    // arr  u32[256]                           1,024
#define OFF_SYN  11777024u    // syn: [0..7]=xcl claim, [8]=epoch           64

__device__ __forceinline__ float fast_tanh(float x) {
  float e = __expf(2.0f * x);
  return 1.0f - __fdividef(2.0f, e + 1.0f);
}

__device__ __forceinline__ void bsplit(float x, u16& hi, u16& lo) {
  __hip_bfloat16 h = __float2bfloat16(x);
  float hf = __bfloat162float(h);
  __hip_bfloat16 l = __float2bfloat16(x - hf);
  hi = *(u16*)&h;
  lo = *(u16*)&l;
}

// ---- cache-scope-parametric helpers ----------------------------------------
// LM=true: sc0 only (L1-bypass, served by own XCD L2 — group is XCD-local).
// LM=false: sc0 sc1 (MALL path, R5/R8-proven).
__device__ __forceinline__ void ld8c(bool LM, f32x4 r[8],
    const void* p0, const void* p1, const void* p2, const void* p3,
    const void* p4, const void* p5, const void* p6, const void* p7) {
  if (LM) {
    asm volatile(
      "global_load_dwordx4 %0, %8, off sc0\n\t"
      "global_load_dwordx4 %1, %9, off sc0\n\t"
      "global_load_dwordx4 %2, %10, off sc0\n\t"
      "global_load_dwordx4 %3, %11, off sc0\n\t"
      "global_load_dwordx4 %4, %12, off sc0\n\t"
      "global_load_dwordx4 %5, %13, off sc0\n\t"
      "global_load_dwordx4 %6, %14, off sc0\n\t"
      "global_load_dwordx4 %7, %15, off sc0\n\t"
      "s_waitcnt vmcnt(0)"
      : "=&v"(r[0]), "=&v"(r[1]), "=&v"(r[2]), "=&v"(r[3]),
        "=&v"(r[4]), "=&v"(r[5]), "=&v"(r[6]), "=&v"(r[7])
      : "v"(p0), "v"(p1), "v"(p2), "v"(p3), "v"(p4), "v"(p5), "v"(p6), "v"(p7)
      : "memory");
  } else {
    asm volatile(
      "global_load_dwordx4 %0, %8, off sc0 sc1\n\t"
      "global_load_dwordx4 %1, %9, off sc0 sc1\n\t"
      "global_load_dwordx4 %2, %10, off sc0 sc1\n\t"
      "global_load_dwordx4 %3, %11, off sc0 sc1\n\t"
      "global_load_dwordx4 %4, %12, off sc0 sc1\n\t"
      "global_load_dwordx4 %5, %13, off sc0 sc1\n\t"
      "global_load_dwordx4 %6, %14, off sc0 sc1\n\t"
      "global_load_dwordx4 %7, %15, off sc0 sc1\n\t"
      "s_waitcnt vmcnt(0)"
      : "=&v"(r[0]), "=&v"(r[1]), "=&v"(r[2]), "=&v"(r[3]),
        "=&v"(r[4]), "=&v"(r[5]), "=&v"(r[6]), "=&v"(r[7])
      : "v"(p0), "v"(p1), "v"(p2), "v"(p3), "v"(p4), "v"(p5), "v"(p6), "v"(p7)
      : "memory");
  }
}

__device__ __forceinline__ void st8b(bool LM, void* p, u32x2 v) {
  if (LM) asm volatile("global_store_dwordx2 %0, %1, off sc0" :: "v"(p), "v"(v) : "memory");
  else    asm volatile("global_store_dwordx2 %0, %1, off sc0 sc1" :: "v"(p), "v"(v) : "memory");
}

__device__ __forceinline__ u32x2 ld2c(bool LM, const void* p) {
  u32x2 v;
  if (LM) asm volatile("global_load_dwordx2 %0, %1, off sc0\n\ts_waitcnt vmcnt(0)"
                       : "=v"(v) : "v"(p) : "memory");
  else    asm volatile("global_load_dwordx2 %0, %1, off sc0 sc1\n\ts_waitcnt vmcnt(0)"
                       : "=v"(v) : "v"(p) : "memory");
  return v;
}

__device__ __forceinline__ u32 ld1g(const u32* p) {
  u32 v;
  asm volatile("global_load_dword %0, %1, off sc0 sc1\n\ts_waitcnt vmcnt(0)"
               : "=v"(v) : "v"(p) : "memory");
  return v;
}

__device__ __forceinline__ void st1g(u32* p, u32 v) {
  asm volatile("global_store_dword %0, %1, off sc0 sc1" :: "v"(p), "v"(v) : "memory");
}

// ---------------------------------------------------------------------------
// dXr[sub][b][c(20 pad)] = dX * (h/2)          (validated R4-R8)
__global__ void k_dx(const float* __restrict__ ts, const float* __restrict__ us,
                     float* __restrict__ dXr) {
  int idx = blockIdx.x * 256 + threadIdx.x;     // 1,300,480 exact
  int c   = idx % 20;
  int t2  = idx / 20;
  int b   = t2 & 255;
  int sub = t2 >> 8;
  if (c >= C_) { dXr[idx] = 0.f; return; }
  int s = sub >> 1, j = sub & 1;
  float t_s = ts[s * B_], t_n = ts[(s + 1) * B_];
  float h = t_n - t_s;
  float xi, xn;
  if (c == 0) { xi = ts[s * B_ + b]; xn = ts[(s + 1) * B_ + b]; }
  else {
    xi = us[(size_t)s       * 4096 + b * 16 + (c - 1)];
    xn = us[(size_t)(s + 1) * 4096 + b * 16 + (c - 1)];
  }
  float mn = (xn - xi) / h;
  float mi;
  if (s == 0) mi = mn;
  else {
    float hp = t_s - ts[(s - 1) * B_];
    float xp = (c == 0) ? ts[(s - 1) * B_ + b]
                        : us[(size_t)(s - 1) * 4096 + b * 16 + (c - 1)];
    mi = (xi - xp) / hp;
  }
  float c2 = 3.f * (xn - xi) / (h * h) - (2.f * mi + mn) / h;
  float c3 = 2.f * (xi - xn) / (h * h * h) + (mi + mn) / (h * h);
  float u  = j ? 0.5f * h : 0.f;
  float dX = mi + 2.f * c2 * u + 3.f * c3 * u * u;
  dXr[idx] = dX * 0.5f * h;
}

// ---------------------------------------------------------------------------
// W2 A-frags per rank (validated): A[m=col(160: 8h x 20pad)][k=256].
__global__ void k_w2f(const float* __restrict__ W2,
                      u16* __restrict__ WH, u16* __restrict__ WL) {
  int idx = blockIdx.x * 256 + threadIdx.x;     // 1,310,720 (grid 5120)
  int e = idx & 7, lane = (idx >> 3) & 63, kt = (idx >> 9) & 7;
  int t = idx >> 12;
  int mt = t % 10, r = t / 10;
  int col = mt * 16 + (lane & 15);
  int hl = col / 20, c = col - hl * 20;
  int k = kt * 32 + 4 * (lane >> 4) + (e & 3) + 16 * (e >> 2);
  float v = (c < C_) ? W2[(size_t)k * (H_ * C_) + (r * 8 + hl) * C_ + c] : 0.f;
  u16 hi, lo; bsplit(v, hi, lo);
  WH[idx] = hi; WL[idx] = lo;
}

// W1 A-frags (validated): A[m=ho(256)][k=h_in(256)], [16 mtg][8 kt][64][8].
__global__ void k_w1f(const float* __restrict__ W1,
                      u16* __restrict__ WH, u16* __restrict__ WL) {
  int idx = blockIdx.x * 256 + threadIdx.x;     // 65536 (grid 256)
  int e = idx & 7, lane = (idx >> 3) & 63, kt = (idx >> 9) & 7, mtg = idx >> 12;
  int m = mtg * 16 + (lane & 15);
  int k = kt * 32 + 4 * (lane >> 4) + (e & 3) + 16 * (e >> 2);
  float v = W1[k * 256 + m];
  u16 hi, lo; bsplit(v, hi, lo);
  WH[idx] = hi; WL[idx] = lo;
}

// dec_W A-frags (validated): A[m=y(16)][k=h(256)].
__global__ void k_def(const float* __restrict__ decW,
                      u16* __restrict__ DH, u16* __restrict__ DL) {
  int idx = blockIdx.x * 256 + threadIdx.x;     // 4096 (grid 16)
  int e = idx & 7, lane = (idx >> 3) & 63, kt = idx >> 9;
  int y = lane & 15;
  int k = kt * 32 + 4 * (lane >> 4) + (e & 3) + 16 * (e >> 2);
  float v = decW[k * 16 + y];
  u16 hi, lo; bsplit(v, hi, lo);
  DH[idx] = hi; DL[idx] = lo;
}

// Per-launch: zero the 8 claim counters; bump the epoch counter once.
__global__ void k_syn0(u32* syn) {
  int i = threadIdx.x;
  if (i < 8) {
    u32 z = 0;
    st1g(syn + i, z);
  } else if (i == 8) {
    __hip_atomic_fetch_add(syn + 8, 1u, __ATOMIC_RELAXED, __HIP_MEMORY_SCOPE_AGENT);
  }
}

// ---------------------------------------------------------------------------
// Persistent kernel, 256 blocks.
// Startup: claim (xcd, slot) via device-scope atomic; arrival barrier on
// epoch-stamped flags; if every XCD claimed exactly 32 blocks -> LOCAL mode
// (group = XCD, all z/flag traffic sc0-only = own-L2 coherent), else MALL
// mode (group = blockIdx>>5, sc0 sc1 — the R8-proven path). Separate buffers
// per mode prevent stale-dirty-line ghosts across replays. All flags carry
// {epoch, step} and are validated by epoch EQUALITY (poison/replay-proof).
__global__ __launch_bounds__(256, 1)
void k_ode5(char* __restrict__ wsb, const float* __restrict__ enc_b,
            const float* __restrict__ f_b1, const float* __restrict__ f_b2,
            const float* __restrict__ dec_b, float* __restrict__ out) {
  const int tid = threadIdx.x, lane = tid & 63, kq = tid >> 6;
  const int gg = lane >> 4, c16 = lane & 15;

  __shared__ __align__(16) char smem[116368];
  float* b1L = (float*)(smem + 114688);          // 256 f32
  float* b2L = (float*)(smem + 115712);          // 160 f32
  u32*  roleS = (u32*)(smem + 116352);           // grp, rank, LM, ep

  u32* syn = (u32*)(wsb + OFF_SYN);
  u32* arr = (u32*)(wsb + OFF_ARR);

  // ---- startup: claim + arrival + mode consensus ----
  if (tid == 0) {
    u32 ep = __hip_atomic_load(syn + 8, __ATOMIC_RELAXED, __HIP_MEMORY_SCOPE_AGENT);
    u32 xc; asm volatile("s_getreg_b32 %0, hwreg(HW_REG_XCC_ID)" : "=s"(xc));
    xc &= 7;
    u32 one = 1, slot;
    asm volatile("global_atomic_add %0, %1, %2, off sc0 sc1\n\ts_waitcnt vmcnt(0)"
                 : "=v"(slot) : "v"(syn + xc), "v"(one) : "memory");
    st1g(arr + blockIdx.x, ep);                  // claim landed before arrive
    roleS[0] = xc; roleS[1] = slot; roleS[3] = ep;
  }
  __syncthreads();
  {
    u32 ep = roleS[3];
    if (kq == 0) {                               // wave0: wait all 256 arrived
      u32 guard = 0;
      for (;;) {
        u32 a0 = ld1g(arr + lane);
        u32 a1 = ld1g(arr + lane + 64);
        u32 a2 = ld1g(arr + lane + 128);
        u32 a3 = ld1g(arr + lane + 192);
        int ok = (a0 == ep) & (a1 == ep) & (a2 == ep) & (a3 == ep);
        if (__all(ok)) break;
        __builtin_amdgcn_s_sleep(2);
        if (++guard > (1u << 22)) break;
      }
    }
    if (tid == 0) {                              // balance -> mode consensus
      u32 bal = 1;
      #pragma unroll
      for (int i = 0; i < 8; ++i) bal &= (ld1g(syn + i) == 32u);
      u32 slot = roleS[1];
      bal &= (slot < 32u);
      roleS[2] = bal;
      if (!bal) { roleS[0] = blockIdx.x >> 5; roleS[1] = blockIdx.x & 31; }
    }
  }
  __syncthreads();
  const int grp = roleS[0], rank = roleS[1];
  const bool LM = (roleS[2] != 0);
  const u32 ep = roleS[3];

  // ---- one-time LDS + persistent fragments ----
  b1L[tid] = f_b1[tid];
  if (tid < 160) { int hl = tid / 20, c = tid - hl * 20;
                   b2L[tid] = (c < C_) ? f_b2[(rank * 8 + hl) * C_ + c] : 0.f; }

  const bf16x8* W2Hg = (const bf16x8*)(wsb + OFF_W2H);
  const bf16x8* W2Lg = (const bf16x8*)(wsb + OFF_W2L);
  const bf16x8* W1Hg = (const bf16x8*)(wsb + OFF_W1H);
  const bf16x8* W1Lg = (const bf16x8*)(wsb + OFF_W1L);
  const bf16x8* DHg  = (const bf16x8*)(wsb + OFF_DEH);
  const bf16x8* DLg  = (const bf16x8*)(wsb + OFF_DEL);
  const float*  dXr  = (const float*)(wsb + OFF_DXR);
  u16* zbH = (u16*)(wsb + (LM ? OFF_ZLH : OFF_ZMH));
  u16* zbL = (u16*)(wsb + (LM ? OFF_ZLL : OFF_ZML));
  u32x2* flg = (u32x2*)(wsb + (LM ? OFF_FLL : OFF_FLM)) + grp * 32;

  // W2-hi persistent: 80 VGPR. W1-hi persistent: 128 VGPR (1 wave/SIMD -> 512 cap).
  bf16x8 wHi[2][10];
  #pragma unroll
  for (int ktl = 0; ktl < 2; ++ktl)
    #pragma unroll
    for (int mt = 0; mt < 10; ++mt)
      wHi[ktl][mt] = W2Hg[((rank * 10 + mt) * 8 + kq * 2 + ktl) * 64 + lane];
  bf16x8 w1hi[4][8];
  #pragma unroll
  for (int mm = 0; mm < 4; ++mm)
    #pragma unroll
    for (int kt = 0; kt < 8; ++kt)
      w1hi[mm][kt] = W1Hg[((4 * kq + mm) * 8 + kt) * 64 + lane];

  // producer-side store geometry (derived & checked vs R8 mapping)
  const int kt2 = rank >> 2;
  const int r8  = (rank & 3) * 8;
  const int ebase = (r8 & 16) ? 4 : 0;
  const int lpb   = c16 + ((r8 & 8) ? 32 : 0);

  // ---- z0 init (in-kernel, both modes): z0[h] = enc_b[h] ----
  float zreg[8];
  if (kq < 2) {
    #pragma unroll
    for (int hh = 0; hh < 8; ++hh) zreg[hh] = enc_b[rank * 8 + hh];
    if (gg == 0) {
      u16* zdH = zbH + (size_t)(0 * NGRP + grp) * 8192;   // buf0, u16 units
      u16* zdL = zbL + (size_t)(0 * NGRP + grp) * 8192;
      #pragma unroll
      for (int q = 0; q < 2; ++q) {
        u16 h0,l0,h1,l1,h2,l2,h3,l3;
        bsplit(zreg[q*4+0], h0, l0); bsplit(zreg[q*4+1], h1, l1);
        bsplit(zreg[q*4+2], h2, l2); bsplit(zreg[q*4+3], h3, l3);
        u32x2 vh, vl;
        vh[0] = (u32)h0 | ((u32)h1 << 16); vh[1] = (u32)h2 | ((u32)h3 << 16);
        vl[0] = (u32)l0 | ((u32)l1 << 16); vl[1] = (u32)l2 | ((u32)l3 << 16);
        int fi = ((kt2 * 2 + kq) * 64 + lpb + 16 * q) * 8 + ebase;
        st8b(LM, zdH + fi, vh);
        st8b(LM, zdL + fi, vl);
      }
    }
  }
  asm volatile("s_waitcnt vmcnt(0)" ::: "memory");
  __syncthreads();
  if (tid == 0) { u32x2 f; f[0] = 0u; f[1] = ep; st8b(LM, flg + rank, f); }

  for (int sub = 0; ; ++sub) {
    // ---- group barrier: all 32 ranks at {ep, >= sub} ----
    if (kq == 0) {
      u32 guard = 0;
      for (;;) {
        u32x2 v = ld2c(LM, flg + (lane & 31));
        int ok = (v[1] == ep) & (v[0] >= (u32)sub);
        if (__all(ok)) break;
        __builtin_amdgcn_s_sleep(1);
        if (++guard > (1u << 16)) break;
      }
    }
    __syncthreads();

    // ---- gather this wave's kt-pair of z frags (hi+lo), one batched RT ----
    {
      const f32x4* zh = (const f32x4*)(zbH + ((size_t)(sub & 1) * NGRP + grp) * 8192);
      const f32x4* zl = (const f32x4*)(zbL + ((size_t)(sub & 1) * NGRP + grp) * 8192);
      int f0 = ((2 * kq + 0) * 2 + 0) * 64 + lane;
      int f1 = ((2 * kq + 0) * 2 + 1) * 64 + lane;
      int f2 = ((2 * kq + 1) * 2 + 0) * 64 + lane;
      int f3 = ((2 * kq + 1) * 2 + 1) * 64 + lane;
      f32x4 r[8];
      ld8c(LM, r, zh + f0, zh + f1, zh + f2, zh + f3,
                  zl + f0, zl + f1, zl + f2, zl + f3);
      ((f32x4*)smem)[f0] = r[0];           ((f32x4*)smem)[f1] = r[1];
      ((f32x4*)smem)[f2] = r[2];           ((f32x4*)smem)[f3] = r[3];
      ((f32x4*)(smem + 16384))[f0] = r[4]; ((f32x4*)(smem + 16384))[f1] = r[5];
      ((f32x4*)(smem + 16384))[f2] = r[6]; ((f32x4*)(smem + 16384))[f3] = r[7];
    }
    __syncthreads();

    const bf16x8* zHl = (const bf16x8*)smem;
    const bf16x8* zLl = (const bf16x8*)(smem + 16384);
    f32x4* red4 = (f32x4*)(smem + 32768);

    // ---- decode (even subs): out[sub/2] = z @ decW + dec_b; rank0 stores ---
    if ((sub & 1) == 0) {
      f32x4 ad0 = (f32x4){0.f,0.f,0.f,0.f}, ad1 = (f32x4){0.f,0.f,0.f,0.f};
      #pragma unroll
      for (int ktl = 0; ktl < 2; ++ktl) {
        int kt = kq * 2 + ktl;
        bf16x8 dh = DHg[kt * 64 + lane], dl = DLg[kt * 64 + lane];
        bf16x8 zh0 = zHl[(kt * 2 + 0) * 64 + lane], zl0 = zLl[(kt * 2 + 0) * 64 + lane];
        bf16x8 zh1 = zHl[(kt * 2 + 1) * 64 + lane], zl1 = zLl[(kt * 2 + 1) * 64 + lane];
        ad0 = __builtin_amdgcn_mfma_f32_16x16x32_bf16(dh, zh0, ad0, 0, 0, 0);
        ad0 = __builtin_amdgcn_mfma_f32_16x16x32_bf16(dh, zl0, ad0, 0, 0, 0);
        ad0 = __builtin_amdgcn_mfma_f32_16x16x32_bf16(dl, zh0, ad0, 0, 0, 0);
        ad1 = __builtin_amdgcn_mfma_f32_16x16x32_bf16(dh, zh1, ad1, 0, 0, 0);
        ad1 = __builtin_amdgcn_mfma_f32_16x16x32_bf16(dh, zl1, ad1, 0, 0, 0);
        ad1 = __builtin_amdgcn_mfma_f32_16x16x32_bf16(dl, zh1, ad1, 0, 0, 0);
      }
      if (kq) {
        red4[((kq - 1) * 2 + 0) * 64 + lane] = ad0;
        red4[((kq - 1) * 2 + 1) * 64 + lane] = ad1;
      }
      __syncthreads();
      if (kq == 0 && rank == 0) {
        #pragma unroll
        for (int q = 0; q < 3; ++q) {
          ad0 += red4[(q * 2 + 0) * 64 + lane];
          ad1 += red4[(q * 2 + 1) * 64 + lane];
        }
        float4 q0, q1;
        q0.x = ad0[0] + dec_b[4 * gg + 0]; q0.y = ad0[1] + dec_b[4 * gg + 1];
        q0.z = ad0[2] + dec_b[4 * gg + 2]; q0.w = ad0[3] + dec_b[4 * gg + 3];
        q1.x = ad1[0] + dec_b[4 * gg + 0]; q1.y = ad1[1] + dec_b[4 * gg + 1];
        q1.z = ad1[2] + dec_b[4 * gg + 2]; q1.w = ad1[3] + dec_b[4 * gg + 3];
        size_t ro = (size_t)(sub >> 1) * 4096;
        *(float4*)(out + ro + (grp * 32 +      c16) * 16 + 4 * gg) = q0;
        *(float4*)(out + ro + (grp * 32 + 16 + c16) * 16 + 4 * gg) = q1;
      }
      __syncthreads();
    }
    if (sub == NSUB) break;

    // ---- phase A: wave kq computes hdn rows ho in [64kq, 64kq+64) ----
    // W1-hi from VGPRs (persistent); W1-lo streamed from L2.
    f32x4 aa[4][2];
    #pragma unroll
    for (int mm = 0; mm < 4; ++mm) {
      aa[mm][0] = (f32x4){0.f,0.f,0.f,0.f};
      aa[mm][1] = (f32x4){0.f,0.f,0.f,0.f};
    }
    #pragma unroll
    for (int kt = 0; kt < 8; ++kt) {
      bf16x8 zh0 = zHl[(kt * 2 + 0) * 64 + lane], zl0 = zLl[(kt * 2 + 0) * 64 + lane];
      bf16x8 zh1 = zHl[(kt * 2 + 1) * 64 + lane], zl1 = zLl[(kt * 2 + 1) * 64 + lane];
      #pragma unroll
      for (int mm = 0; mm < 4; ++mm) {
        bf16x8 wh = w1hi[mm][kt];
        bf16x8 wl = W1Lg[((4 * kq + mm) * 8 + kt) * 64 + lane];
        aa[mm][0] = __builtin_amdgcn_mfma_f32_16x16x32_bf16(wh, zh0, aa[mm][0], 0, 0, 0);
        aa[mm][0] = __builtin_amdgcn_mfma_f32_16x16x32_bf16(wh, zl0, aa[mm][0], 0, 0, 0);
        aa[mm][0] = __builtin_amdgcn_mfma_f32_16x16x32_bf16(wl, zh0, aa[mm][0], 0, 0, 0);
        aa[mm][1] = __builtin_amdgcn_mfma_f32_16x16x32_bf16(wh, zh1, aa[mm][1], 0, 0, 0);
        aa[mm][1] = __builtin_amdgcn_mfma_f32_16x16x32_bf16(wh, zl1, aa[mm][1], 0, 0, 0);
        aa[mm][1] = __builtin_amdgcn_mfma_f32_16x16x32_bf16(wl, zh1, aa[mm][1], 0, 0, 0);
      }
    }

    // ---- pure-register repack: C(mm,nt) -> B-frag (kt2 = 2kq + mm>>1) ----
    bf16x8 hH[2][2], hL[2][2];
    #pragma unroll
    for (int mm = 0; mm < 4; ++mm)
      #pragma unroll
      for (int nt = 0; nt < 2; ++nt)
        #pragma unroll
        for (int r = 0; r < 4; ++r) {
          float v = aa[mm][nt][r] + b1L[kq * 64 + mm * 16 + 4 * gg + r];
          v = fmaxf(v, 0.f);
          u16 hi, lo; bsplit(v, hi, lo);
          hH[mm >> 1][nt][r + 4 * (mm & 1)] = (short)hi;
          hL[mm >> 1][nt][r + 4 * (mm & 1)] = (short)lo;
        }

    // ---- phase B: [160 col][32 b]; W2-hi persistent, W2-lo streamed ----
    f32x4 ab[10][2];
    #pragma unroll
    for (int mt = 0; mt < 10; ++mt) {
      ab[mt][0] = (f32x4){0.f,0.f,0.f,0.f};
      ab[mt][1] = (f32x4){0.f,0.f,0.f,0.f};
    }
    #pragma unroll
    for (int ktl = 0; ktl < 2; ++ktl)
      #pragma unroll
      for (int mt = 0; mt < 10; ++mt) {
        bf16x8 wlo = W2Lg[((rank * 10 + mt) * 8 + kq * 2 + ktl) * 64 + lane];
        ab[mt][0] = __builtin_amdgcn_mfma_f32_16x16x32_bf16(wHi[ktl][mt], hH[ktl][0], ab[mt][0], 0, 0, 0);
        ab[mt][0] = __builtin_amdgcn_mfma_f32_16x16x32_bf16(wHi[ktl][mt], hL[ktl][0], ab[mt][0], 0, 0, 0);
        ab[mt][0] = __builtin_amdgcn_mfma_f32_16x16x32_bf16(wlo,          hH[ktl][0], ab[mt][0], 0, 0, 0);
        ab[mt][1] = __builtin_amdgcn_mfma_f32_16x16x32_bf16(wHi[ktl][mt], hH[ktl][1], ab[mt][1], 0, 0, 0);
        ab[mt][1] = __builtin_amdgcn_mfma_f32_16x16x32_bf16(wHi[ktl][mt], hL[ktl][1], ab[mt][1], 0, 0, 0);
        ab[mt][1] = __builtin_amdgcn_mfma_f32_16x16x32_bf16(wlo,          hH[ktl][1], ab[mt][1], 0, 0, 0);
      }

    // ---- cross-wave K reduce (conflict-free lane*16 layout) ----
    #pragma unroll
    for (int mt = 0; mt < 10; ++mt) {
      red4[(kq * 20 + mt * 2 + 0) * 64 + lane] = ab[mt][0];
      red4[(kq * 20 + mt * 2 + 1) * 64 + lane] = ab[mt][1];
    }
    __syncthreads();

    // ---- epilogue on waves 0,1 (w = nt): tanh, c-contract, z update ----
    if (kq < 2) {
      const int w = kq;
      float ph[8] = {0.f,0.f,0.f,0.f,0.f,0.f,0.f,0.f};
      #pragma unroll
      for (int mt = 0; mt < 10; ++mt) {
        f32x4 s = red4[(0 * 20 + mt * 2 + w) * 64 + lane]
                + red4[(1 * 20 + mt * 2 + w) * 64 + lane]
                + red4[(2 * 20 + mt * 2 + w) * 64 + lane]
                + red4[(3 * 20 + mt * 2 + w) * 64 + lane];
        int col0 = mt * 16 + 4 * gg;
        int hl_  = col0 / 20;
        int c0   = col0 - hl_ * 20;
        float4 b2v = *(const float4*)&b2L[col0];
        float4 dxv = *(const float4*)(dXr +
            ((size_t)sub * 256 + grp * 32 + w * 16 + c16) * 20 + c0);
        float t0 = fast_tanh(s[0] + b2v.x);
        float t1 = fast_tanh(s[1] + b2v.y);
        float t2 = fast_tanh(s[2] + b2v.z);
        float t3 = fast_tanh(s[3] + b2v.w);
        float contrib = fmaf(t0, dxv.x, fmaf(t1, dxv.y, fmaf(t2, dxv.z, t3 * dxv.w)));
        #pragma unroll
        for (int hh = 0; hh < 8; ++hh)
          ph[hh] += (hl_ == hh) ? contrib : 0.f;
      }
      #pragma unroll
      for (int hh = 0; hh < 8; ++hh) {
        float v = ph[hh];
        v += __shfl_xor(v, 16);
        v += __shfl_xor(v, 32);
        zreg[hh] += v;
      }
      if (gg == 0) {
        u16* zdH = zbH + ((size_t)((sub + 1) & 1) * NGRP + grp) * 8192;
        u16* zdL = zbL + ((size_t)((sub + 1) & 1) * NGRP + grp) * 8192;
        #pragma unroll
        for (int q = 0; q < 2; ++q) {
          u16 h0,l0,h1,l1,h2,l2,h3,l3;
          bsplit(zreg[q*4+0], h0, l0); bsplit(zreg[q*4+1], h1, l1);
          bsplit(zreg[q*4+2], h2, l2); bsplit(zreg[q*4+3], h3, l3);
          u32x2 vh, vl;
          vh[0] = (u32)h0 | ((u32)h1 << 16); vh[1] = (u32)h2 | ((u32)h3 << 16);
          vl[0] = (u32)l0 | ((u32)l1 << 16); vl[1] = (u32)l2 | ((u32)l3 << 16);
          int fi = ((kt2 * 2 + w) * 64 + lpb + 16 * q) * 8 + ebase;
          st8b(LM, zdH + fi, vh);
          st8b(LM, zdL + fi, vl);
        }
      }
    }

    // ---- arrive: drain stores, then flag = {ep, sub+1} ----
    asm volatile("s_waitcnt vmcnt(0)" ::: "memory");
    __syncthreads();
    if (tid == 0) {
      u32x2 f; f[0] = (u32)(sub + 1); f[1] = ep;
      st8b(LM, flg + rank, f);
    }
  }
}

// ---------------------------------------------------------------------------
extern "C" void kernel_launch(void* const* d_in, const int* in_sizes, int n_in,
                              void* d_out, int out_size, void* d_ws, size_t ws_size,
                              hipStream_t stream) {
  const float* ts    = (const float*)d_in[0];
  const float* us    = (const float*)d_in[1];
  const float* enc_b = (const float*)d_in[5];
  const float* dec_W = (const float*)d_in[6];
  const float* dec_b = (const float*)d_in[7];
  const float* f_W1  = (const float*)d_in[8];
  const float* f_b1  = (const float*)d_in[9];
  const float* f_W2  = (const float*)d_in[10];
  const float* f_b2  = (const float*)d_in[11];
  float* out = (float*)d_out;
  char* wsb = (char*)d_ws;

  k_dx   <<<5080, 256, 0, stream>>>(ts, us, (float*)(wsb + OFF_DXR));
  k_w2f  <<<5120, 256, 0, stream>>>(f_W2, (u16*)(wsb + OFF_W2H), (u16*)(wsb + OFF_W2L));
  k_w1f  <<<256, 256, 0, stream>>>(f_W1, (u16*)(wsb + OFF_W1H), (u16*)(wsb + OFF_W1L));
  k_def  <<<16, 256, 0, stream>>>(dec_W, (u16*)(wsb + OFF_DEH), (u16*)(wsb + OFF_DEL));
  k_syn0 <<<1, 64, 0, stream>>>((u32*)(wsb + OFF_SYN));

  k_ode5<<<NGRP * RNK, 256, 0, stream>>>(wsb, enc_b, f_b1, f_b2, dec_b, out);
}

// Round 10
// 8714.526 us; speedup vs baseline: 247.2701x; 247.2701x over previous
//
#include <hip/hip_runtime.h>
#include <hip/hip_bf16.h>
#include <cmath>

// L=128, B=256, H=256, C=17, Y=16, N_SUB=2
#define L_   128
#define B_   256
#define H_   256
#define C_   17
#define Y_   16
#define NSUB 254
#define NGRP 16          // groups (b-slabs of 16)
#define RNK  32          // ranks per group (8 h each)

typedef short bf16x8 __attribute__((ext_vector_type(8)));
typedef float f32x4  __attribute__((ext_vector_type(4)));
typedef unsigned int u32x2 __attribute__((ext_vector_type(2)));
typedef unsigned short u16;
typedef unsigned int   u32;

// ---- workspace byte offsets ------------------------------------------------
#define OFF_DXR  0u           // [254][256 b][20 c] f32              5,201,920
#define OFF_W2H  5201920u     // [32 r][10 mt][8 kt][64][8] u16      2,621,440
#define OFF_W2L  7823360u
#define OFF_W1H  10444800u    // [16 mtg][8 kt][64][8] u16             131,072
#define OFF_W1L  10575872u
#define OFF_DEH  10706944u    // [8 kt][64][8] u16                       8,192
#define OFF_DEL  10715136u
#define OFF_ZFH  10723328u    // [2 buf][16 grp][8 kt][64][8] u16      262,144
#define OFF_ZFL  10985472u
#define OFF_FLG  11247616u    // [16 grp][32 rank] u32 (128B line/grp)   2,048

__device__ __forceinline__ float fast_tanh(float x) {
  float e = __expf(2.0f * x);
  return 1.0f - __fdividef(2.0f, e + 1.0f);
}

__device__ __forceinline__ void bsplit(float x, u16& hi, u16& lo) {
  __hip_bfloat16 h = __float2bfloat16(x);
  float hf = __bfloat162float(h);
  __hip_bfloat16 l = __float2bfloat16(x - hf);
  hi = *(u16*)&h;
  lo = *(u16*)&l;
}

// ---- MALL-path (sc0 sc1) helpers — the R5/R8-proven mechanism --------------
__device__ __forceinline__ void ld4c(f32x4 r[4], const void* p0, const void* p1,
                                     const void* p2, const void* p3) {
  asm volatile(
    "global_load_dwordx4 %0, %4, off sc0 sc1\n\t"
    "global_load_dwordx4 %1, %5, off sc0 sc1\n\t"
    "global_load_dwordx4 %2, %6, off sc0 sc1\n\t"
    "global_load_dwordx4 %3, %7, off sc0 sc1\n\t"
    "s_waitcnt vmcnt(0)"
    : "=&v"(r[0]), "=&v"(r[1]), "=&v"(r[2]), "=&v"(r[3])
    : "v"(p0), "v"(p1), "v"(p2), "v"(p3)
    : "memory");
}

__device__ __forceinline__ void st8b(void* p, u32x2 v) {
  asm volatile("global_store_dwordx2 %0, %1, off sc0 sc1" :: "v"(p), "v"(v) : "memory");
}

__device__ __forceinline__ u32 ld1g(const u32* p) {
  u32 v;
  asm volatile("global_load_dword %0, %1, off sc0 sc1\n\ts_waitcnt vmcnt(0)"
               : "=v"(v) : "v"(p) : "memory");
  return v;
}

__device__ __forceinline__ void st1g(u32* p, u32 v) {
  asm volatile("global_store_dword %0, %1, off sc0 sc1" :: "v"(p), "v"(v) : "memory");
}

// ---------------------------------------------------------------------------
// dXr[sub][b][c(20 pad)] = dX * (h/2)          (validated R4-R9)
__global__ void k_dx(const float* __restrict__ ts, const float* __restrict__ us,
                     float* __restrict__ dXr) {
  int idx = blockIdx.x * 256 + threadIdx.x;     // 1,300,480 exact
  int c   = idx % 20;
  int t2  = idx / 20;
  int b   = t2 & 255;
  int sub = t2 >> 8;
  if (c >= C_) { dXr[idx] = 0.f; return; }
  int s = sub >> 1, j = sub & 1;
  float t_s = ts[s * B_], t_n = ts[(s + 1) * B_];
  float h = t_n - t_s;
  float xi, xn;
  if (c == 0) { xi = ts[s * B_ + b]; xn = ts[(s + 1) * B_ + b]; }
  else {
    xi = us[(size_t)s       * 4096 + b * 16 + (c - 1)];
    xn = us[(size_t)(s + 1) * 4096 + b * 16 + (c - 1)];
  }
  float mn = (xn - xi) / h;
  float mi;
  if (s == 0) mi = mn;
  else {
    float hp = t_s - ts[(s - 1) * B_];
    float xp = (c == 0) ? ts[(s - 1) * B_ + b]
                        : us[(size_t)(s - 1) * 4096 + b * 16 + (c - 1)];
    mi = (xi - xp) / hp;
  }
  float c2 = 3.f * (xn - xi) / (h * h) - (2.f * mi + mn) / h;
  float c3 = 2.f * (xi - xn) / (h * h * h) + (mi + mn) / (h * h);
  float u  = j ? 0.5f * h : 0.f;
  float dX = mi + 2.f * c2 * u + 3.f * c3 * u * u;
  dXr[idx] = dX * 0.5f * h;
}

// ---------------------------------------------------------------------------
// W2 A-frags per rank (validated): A[m=col(160: 8h x 20pad)][k=256].
__global__ void k_w2f(const float* __restrict__ W2,
                      u16* __restrict__ WH, u16* __restrict__ WL) {
  int idx = blockIdx.x * 256 + threadIdx.x;     // 1,310,720 (grid 5120)
  int e = idx & 7, lane = (idx >> 3) & 63, kt = (idx >> 9) & 7;
  int t = idx >> 12;
  int mt = t % 10, r = t / 10;
  int col = mt * 16 + (lane & 15);
  int hl = col / 20, c = col - hl * 20;
  int k = kt * 32 + 4 * (lane >> 4) + (e & 3) + 16 * (e >> 2);
  float v = (c < C_) ? W2[(size_t)k * (H_ * C_) + (r * 8 + hl) * C_ + c] : 0.f;
  u16 hi, lo; bsplit(v, hi, lo);
  WH[idx] = hi; WL[idx] = lo;
}

// W1 A-frags (validated): A[m=ho(256)][k=h_in(256)], [16 mtg][8 kt][64][8].
__global__ void k_w1f(const float* __restrict__ W1,
                      u16* __restrict__ WH, u16* __restrict__ WL) {
  int idx = blockIdx.x * 256 + threadIdx.x;     // 65536 (grid 256)
  int e = idx & 7, lane = (idx >> 3) & 63, kt = (idx >> 9) & 7, mtg = idx >> 12;
  int m = mtg * 16 + (lane & 15);
  int k = kt * 32 + 4 * (lane >> 4) + (e & 3) + 16 * (e >> 2);
  float v = W1[k * 256 + m];
  u16 hi, lo; bsplit(v, hi, lo);
  WH[idx] = hi; WL[idx] = lo;
}

// dec_W A-frags (validated): A[m=y(16)][k=h(256)].
__global__ void k_def(const float* __restrict__ decW,
                      u16* __restrict__ DH, u16* __restrict__ DL) {
  int idx = blockIdx.x * 256 + threadIdx.x;     // 4096 (grid 16)
  int e = idx & 7, lane = (idx >> 3) & 63, kt = idx >> 9;
  int y = lane & 15;
  int k = kt * 32 + 4 * (lane >> 4) + (e & 3) + 16 * (e >> 2);
  float v = decW[k * 16 + y];
  u16 hi, lo; bsplit(v, hi, lo);
  DH[idx] = hi; DL[idx] = lo;
}

// z0 frags (buf0): [16 grp][8 kt][64][8], z0[h][b] = enc_b[h].
__global__ void k_initF(const float* __restrict__ enc_b,
                        u16* __restrict__ ZH, u16* __restrict__ ZL) {
  int idx = blockIdx.x * 256 + threadIdx.x;     // 65536 (grid 256)
  int e = idx & 7, lane = (idx >> 3) & 63;
  int kt = (idx >> 9) & 7;
  int h = kt * 32 + 4 * (lane >> 4) + (e & 3) + 16 * (e >> 2);
  float v = enc_b[h];
  u16 hi, lo; bsplit(v, hi, lo);
  ZH[idx] = hi; ZL[idx] = lo;
}

// zero flags through the coherent point (every launch, stream-ordered)
__global__ void k_flg0(u32* f) {
  u32 z = 0;
  st1g(f + threadIdx.x, z);                     // 512 = 16 grp x 32 rank
}

// ---------------------------------------------------------------------------
// Persistent kernel: 512 blocks, 2 per CU (LDS 59KB, launch_bounds(256,2) ->
// residency guaranteed; co-resident pairs overlap each other's MALL waits).
// grp = blk>>5 owns b-slab [16*grp, 16*grp+16); rank = blk&31 owns 8 h.
// Per substep: poll group flag line -> gather z frags (1 batched MALL RT) ->
// LDS -> decode (even) -> phase A (wave kq computes exactly the ho-quarter it
// consumes; pure-register repack) -> phase B (W2-hi persistent in VGPRs) ->
// LDS reduce -> wave0 epilogue -> owner z-store -> vmcnt(0) -> flag store.
__global__ __launch_bounds__(256, 2)
void k_ode6(char* __restrict__ wsb, const float* __restrict__ enc_b,
            const float* __restrict__ f_b1, const float* __restrict__ f_b2,
            const float* __restrict__ dec_b, float* __restrict__ out) {
  const int tid = threadIdx.x, lane = tid & 63, kq = tid >> 6;
  const int grp = blockIdx.x >> 5, rank = blockIdx.x & 31;
  const int gg = lane >> 4, c16 = lane & 15;

  // LDS: zstage hi [0,8K) lo [8K,16K) | red4 40K [16K,56K) | b1L | b2L
  __shared__ __align__(16) char smem[59008];
  float* b1L = (float*)(smem + 57344);          // 256 f32
  float* b2L = (float*)(smem + 58368);          // 160 f32

  b1L[tid] = f_b1[tid];
  if (tid < 160) { int hl = tid / 20, c = tid - hl * 20;
                   b2L[tid] = (c < C_) ? f_b2[(rank * 8 + hl) * C_ + c] : 0.f; }

  const bf16x8* W2Hg = (const bf16x8*)(wsb + OFF_W2H);
  const bf16x8* W2Lg = (const bf16x8*)(wsb + OFF_W2L);
  const bf16x8* W1Hg = (const bf16x8*)(wsb + OFF_W1H);
  const bf16x8* W1Lg = (const bf16x8*)(wsb + OFF_W1L);
  const bf16x8* DHg  = (const bf16x8*)(wsb + OFF_DEH);
  const bf16x8* DLg  = (const bf16x8*)(wsb + OFF_DEL);
  const float*  dXr  = (const float*)(wsb + OFF_DXR);
  u32* flg = (u32*)(wsb + OFF_FLG) + grp * 32;

  // persistent W2-hi frags: [2 ktl][10 mt] = 80 VGPR
  bf16x8 wHi[2][10];
  #pragma unroll
  for (int ktl = 0; ktl < 2; ++ktl)
    #pragma unroll
    for (int mt = 0; mt < 10; ++mt)
      wHi[ktl][mt] = W2Hg[((rank * 10 + mt) * 8 + kq * 2 + ktl) * 64 + lane];

  // producer-side store geometry (R9-validated quad mapping)
  const int kt2 = rank >> 2;
  const int r8  = (rank & 3) * 8;
  const int ebase = (r8 & 16) ? 4 : 0;
  const int lpb   = c16 + ((r8 & 8) ? 32 : 0);

  // fp32 master z (wave 0): z[rank*8+hh][grp*16 + c16]
  float zreg[8];
  if (kq == 0)
    #pragma unroll
    for (int hh = 0; hh < 8; ++hh) zreg[hh] = enc_b[rank * 8 + hh];

  for (int sub = 0; ; ++sub) {
    // ---- group barrier: all 32 ranks' flags >= sub (one line, no atomics) --
    if (kq == 0) {
      u32 guard = 0;
      for (;;) {
        u32 v = ld1g(flg + (lane & 31));
        if (__all((int)(v >= (u32)sub))) break;
        __builtin_amdgcn_s_sleep(1);
        if (++guard > (1u << 17)) break;        // fail-fast
      }
    }
    __syncthreads();

    // ---- gather this wave's kt-pair of z frags (hi+lo), one batched RT ----
    {
      const f32x4* zh = (const f32x4*)(wsb + OFF_ZFH +
                          ((size_t)(sub & 1) * NGRP + grp) * 8192);
      const f32x4* zl = (const f32x4*)(wsb + OFF_ZFL +
                          ((size_t)(sub & 1) * NGRP + grp) * 8192);
      int f0 = (2 * kq + 0) * 64 + lane;
      int f1 = (2 * kq + 1) * 64 + lane;
      f32x4 r[4];
      ld4c(r, zh + f0, zh + f1, zl + f0, zl + f1);
      ((f32x4*)smem)[f0] = r[0];
      ((f32x4*)smem)[f1] = r[1];
      ((f32x4*)(smem + 8192))[f0] = r[2];
      ((f32x4*)(smem + 8192))[f1] = r[3];
    }
    __syncthreads();

    const bf16x8* zHl = (const bf16x8*)smem;
    const bf16x8* zLl = (const bf16x8*)(smem + 8192);
    f32x4* red4 = (f32x4*)(smem + 16384);

    // ---- decode (even subs): out[sub/2] = z @ decW + dec_b; rank0 stores ---
    if ((sub & 1) == 0) {
      f32x4 ad = (f32x4){0.f, 0.f, 0.f, 0.f};
      #pragma unroll
      for (int ktl = 0; ktl < 2; ++ktl) {
        int kt = kq * 2 + ktl;
        bf16x8 dh = DHg[kt * 64 + lane], dl = DLg[kt * 64 + lane];
        bf16x8 zh = zHl[kt * 64 + lane], zl = zLl[kt * 64 + lane];
        ad = __builtin_amdgcn_mfma_f32_16x16x32_bf16(dh, zh, ad, 0, 0, 0);
        ad = __builtin_amdgcn_mfma_f32_16x16x32_bf16(dh, zl, ad, 0, 0, 0);
        ad = __builtin_amdgcn_mfma_f32_16x16x32_bf16(dl, zh, ad, 0, 0, 0);
      }
      if (kq) red4[(kq - 1) * 64 + lane] = ad;
      __syncthreads();
      if (kq == 0 && rank == 0) {
        #pragma unroll
        for (int q = 0; q < 3; ++q) ad += red4[q * 64 + lane];
        float4 q0;
        q0.x = ad[0] + dec_b[4 * gg + 0]; q0.y = ad[1] + dec_b[4 * gg + 1];
        q0.z = ad[2] + dec_b[4 * gg + 2]; q0.w = ad[3] + dec_b[4 * gg + 3];
        *(float4*)(out + (size_t)(sub >> 1) * 4096 +
                   (grp * 16 + c16) * 16 + 4 * gg) = q0;
      }
      __syncthreads();
    }
    if (sub == NSUB) break;

    // ---- phase A: wave kq computes hdn rows ho in [64kq, 64kq+64) ----
    f32x4 aa[4];
    #pragma unroll
    for (int mm = 0; mm < 4; ++mm) aa[mm] = (f32x4){0.f, 0.f, 0.f, 0.f};
    #pragma unroll
    for (int kt = 0; kt < 8; ++kt) {
      bf16x8 zh = zHl[kt * 64 + lane], zl = zLl[kt * 64 + lane];
      #pragma unroll
      for (int mm = 0; mm < 4; ++mm) {
        bf16x8 wh = W1Hg[((4 * kq + mm) * 8 + kt) * 64 + lane];
        bf16x8 wl = W1Lg[((4 * kq + mm) * 8 + kt) * 64 + lane];
        aa[mm] = __builtin_amdgcn_mfma_f32_16x16x32_bf16(wh, zh, aa[mm], 0, 0, 0);
        aa[mm] = __builtin_amdgcn_mfma_f32_16x16x32_bf16(wh, zl, aa[mm], 0, 0, 0);
        aa[mm] = __builtin_amdgcn_mfma_f32_16x16x32_bf16(wl, zh, aa[mm], 0, 0, 0);
      }
    }

    // ---- pure-register repack: C(mm) -> B-frag (kt2 = 2kq + mm>>1) ----
    bf16x8 hH[2], hL[2];
    #pragma unroll
    for (int mm = 0; mm < 4; ++mm)
      #pragma unroll
      for (int r = 0; r < 4; ++r) {
        float v = aa[mm][r] + b1L[kq * 64 + mm * 16 + 4 * gg + r];
        v = fmaxf(v, 0.f);
        u16 hi, lo; bsplit(v, hi, lo);
        hH[mm >> 1][r + 4 * (mm & 1)] = (short)hi;
        hL[mm >> 1][r + 4 * (mm & 1)] = (short)lo;
      }

    // ---- phase B: [160 col][16 b]; W2-hi persistent, W2-lo streamed ----
    f32x4 ab[10];
    #pragma unroll
    for (int mt = 0; mt < 10; ++mt) ab[mt] = (f32x4){0.f, 0.f, 0.f, 0.f};
    #pragma unroll
    for (int ktl = 0; ktl < 2; ++ktl)
      #pragma unroll
      for (int mt = 0; mt < 10; ++mt) {
        bf16x8 wlo = W2Lg[((rank * 10 + mt) * 8 + kq * 2 + ktl) * 64 + lane];
        ab[mt] = __builtin_amdgcn_mfma_f32_16x16x32_bf16(wHi[ktl][mt], hH[ktl], ab[mt], 0, 0, 0);
        ab[mt] = __builtin_amdgcn_mfma_f32_16x16x32_bf16(wHi[ktl][mt], hL[ktl], ab[mt], 0, 0, 0);
        ab[mt] = __builtin_amdgcn_mfma_f32_16x16x32_bf16(wlo,          hH[ktl], ab[mt], 0, 0, 0);
      }

    // ---- cross-wave K reduce (conflict-free lane*16 layout) ----
    #pragma unroll
    for (int mt = 0; mt < 10; ++mt)
      red4[(kq * 10 + mt) * 64 + lane] = ab[mt];
    __syncthreads();

    // ---- epilogue on wave 0: tanh, c-contract, z update, frag store ----
    if (kq == 0) {
      float ph[8] = {0.f,0.f,0.f,0.f,0.f,0.f,0.f,0.f};
      #pragma unroll
      for (int mt = 0; mt < 10; ++mt) {
        f32x4 s = red4[(0 * 10 + mt) * 64 + lane]
                + red4[(1 * 10 + mt) * 64 + lane]
                + red4[(2 * 10 + mt) * 64 + lane]
                + red4[(3 * 10 + mt) * 64 + lane];
        int col0 = mt * 16 + 4 * gg;
        int hl_  = col0 / 20;
        int c0   = col0 - hl_ * 20;
        float4 b2v = *(const float4*)&b2L[col0];
        float4 dxv = *(const float4*)(dXr +
            ((size_t)sub * 256 + grp * 16 + c16) * 20 + c0);
        float t0 = fast_tanh(s[0] + b2v.x);
        float t1 = fast_tanh(s[1] + b2v.y);
        float t2 = fast_tanh(s[2] + b2v.z);
        float t3 = fast_tanh(s[3] + b2v.w);
        float contrib = fmaf(t0, dxv.x, fmaf(t1, dxv.y, fmaf(t2, dxv.z, t3 * dxv.w)));
        #pragma unroll
        for (int hh = 0; hh < 8; ++hh)
          ph[hh] += (hl_ == hh) ? contrib : 0.f;
      }
      #pragma unroll
      for (int hh = 0; hh < 8; ++hh) {
        float v = ph[hh];
        v += __shfl_xor(v, 16);
        v += __shfl_xor(v, 32);
        zreg[hh] += v;
      }
      if (gg == 0) {
        u16* zdH = (u16*)(wsb + OFF_ZFH) + ((size_t)((sub + 1) & 1) * NGRP + grp) * 4096;
        u16* zdL = (u16*)(wsb + OFF_ZFL) + ((size_t)((sub + 1) & 1) * NGRP + grp) * 4096;
        #pragma unroll
        for (int q = 0; q < 2; ++q) {
          u16 h0,l0,h1,l1,h2,l2,h3,l3;
          bsplit(zreg[q*4+0], h0, l0); bsplit(zreg[q*4+1], h1, l1);
          bsplit(zreg[q*4+2], h2, l2); bsplit(zreg[q*4+3], h3, l3);
          u32x2 vh, vl;
          vh[0] = (u32)h0 | ((u32)h1 << 16); vh[1] = (u32)h2 | ((u32)h3 << 16);
          vl[0] = (u32)l0 | ((u32)l1 << 16); vl[1] = (u32)l2 | ((u32)l3 << 16);
          int fi = (kt2 * 64 + lpb + 16 * q) * 8 + ebase;
          st8b(zdH + fi, vh);
          st8b(zdL + fi, vl);
        }
      }
    }

    // ---- arrive: drain stores, then flag = sub+1 ----
    asm volatile("s_waitcnt vmcnt(0)" ::: "memory");
    __syncthreads();
    if (tid == 0) st1g(flg + rank, (u32)(sub + 1));
  }
}

// ---------------------------------------------------------------------------
extern "C" void kernel_launch(void* const* d_in, const int* in_sizes, int n_in,
                              void* d_out, int out_size, void* d_ws, size_t ws_size,
                              hipStream_t stream) {
  const float* ts    = (const float*)d_in[0];
  const float* us    = (const float*)d_in[1];
  const float* enc_b = (const float*)d_in[5];
  const float* dec_W = (const float*)d_in[6];
  const float* dec_b = (const float*)d_in[7];
  const float* f_W1  = (const float*)d_in[8];
  const float* f_b1  = (const float*)d_in[9];
  const float* f_W2  = (const float*)d_in[10];
  const float* f_b2  = (const float*)d_in[11];
  float* out = (float*)d_out;
  char* wsb = (char*)d_ws;

  k_dx   <<<5080, 256, 0, stream>>>(ts, us, (float*)(wsb + OFF_DXR));
  k_w2f  <<<5120, 256, 0, stream>>>(f_W2, (u16*)(wsb + OFF_W2H), (u16*)(wsb + OFF_W2L));
  k_w1f  <<<256, 256, 0, stream>>>(f_W1, (u16*)(wsb + OFF_W1H), (u16*)(wsb + OFF_W1L));
  k_def  <<<16, 256, 0, stream>>>(dec_W, (u16*)(wsb + OFF_DEH), (u16*)(wsb + OFF_DEL));
  k_initF<<<256, 256, 0, stream>>>(enc_b, (u16*)(wsb + OFF_ZFH), (u16*)(wsb + OFF_ZFL));
  k_flg0 <<<1, 512, 0, stream>>>((u32*)(wsb + OFF_FLG));

  k_ode6<<<NGRP * RNK, 256, 0, stream>>>(wsb, enc_b, f_b1, f_b2, dec_b, out);
}

// Round 11
// 4414.781 us; speedup vs baseline: 488.0971x; 1.9739x over previous
//
#include <hip/hip_runtime.h>
#include <hip/hip_bf16.h>
#include <cmath>

// L=128, B=256, H=256, C=17, Y=16, N_SUB=2
#define L_   128
#define B_   256
#define H_   256
#define C_   17
#define Y_   16
#define NSUB 254
#define NGRP 16          // groups (b-slabs of 16)
#define RNK  32          // ranks per group (8 h each)

typedef short bf16x8 __attribute__((ext_vector_type(8)));
typedef float f32x4  __attribute__((ext_vector_type(4)));
typedef unsigned int u32x2 __attribute__((ext_vector_type(2)));
typedef unsigned short u16;
typedef unsigned int   u32;

// ---- workspace byte offsets (R10 map) --------------------------------------
#define OFF_DXR  0u           // [254][256 b][20 c] f32              5,201,920
#define OFF_W2H  5201920u     // [32 r][10 mt][8 kt][64][8] u16      2,621,440
#define OFF_W2L  7823360u
#define OFF_W1H  10444800u    // [16 mtg][8 kt][64][8] u16             131,072
#define OFF_W1L  10575872u
#define OFF_DEH  10706944u    // [8 kt][64][8] u16                       8,192
#define OFF_DEL  10715136u
#define OFF_ZFH  10723328u    // [2 buf][16 grp][8 kt][64][8] u16      262,144
#define OFF_ZFL  10985472u
#define OFF_FLG  11247616u    // [16 grp][32 rank] u32                   2,048

__device__ __forceinline__ float fast_tanh(float x) {
  float e = __expf(2.0f * x);
  return 1.0f - __fdividef(2.0f, e + 1.0f);
}

__device__ __forceinline__ void bsplit(float x, u16& hi, u16& lo) {
  __hip_bfloat16 h = __float2bfloat16(x);
  float hf = __bfloat162float(h);
  __hip_bfloat16 l = __float2bfloat16(x - hf);
  hi = *(u16*)&h;
  lo = *(u16*)&l;
}

// ---- MALL-path (sc0 sc1) helpers — R5/R8/R10-proven ------------------------
// issue 4 b128 loads WITHOUT waitcnt (overlap window); wt4 creates the data
// dependency so no read of r[] can be scheduled before the wait.
__device__ __forceinline__ void ld4c_nw(f32x4 r[4], const void* p0, const void* p1,
                                        const void* p2, const void* p3) {
  asm volatile(
    "global_load_dwordx4 %0, %4, off sc0 sc1\n\t"
    "global_load_dwordx4 %1, %5, off sc0 sc1\n\t"
    "global_load_dwordx4 %2, %6, off sc0 sc1\n\t"
    "global_load_dwordx4 %3, %7, off sc0 sc1"
    : "=&v"(r[0]), "=&v"(r[1]), "=&v"(r[2]), "=&v"(r[3])
    : "v"(p0), "v"(p1), "v"(p2), "v"(p3)
    : "memory");
}

__device__ __forceinline__ void wt4(f32x4 r[4]) {
  asm volatile("s_waitcnt vmcnt(0)"
               : "+v"(r[0]), "+v"(r[1]), "+v"(r[2]), "+v"(r[3]) :: "memory");
}

__device__ __forceinline__ void st8b(void* p, u32x2 v) {
  asm volatile("global_store_dwordx2 %0, %1, off sc0 sc1" :: "v"(p), "v"(v) : "memory");
}

__device__ __forceinline__ u32 ld1g(const u32* p) {
  u32 v;
  asm volatile("global_load_dword %0, %1, off sc0 sc1\n\ts_waitcnt vmcnt(0)"
               : "=v"(v) : "v"(p) : "memory");
  return v;
}

__device__ __forceinline__ void st1g(u32* p, u32 v) {
  asm volatile("global_store_dword %0, %1, off sc0 sc1" :: "v"(p), "v"(v) : "memory");
}

// ---------------------------------------------------------------------------
// dXr[sub][b][c(20 pad)] = dX * (h/2)          (validated R4-R10)
__global__ void k_dx(const float* __restrict__ ts, const float* __restrict__ us,
                     float* __restrict__ dXr) {
  int idx = blockIdx.x * 256 + threadIdx.x;     // 1,300,480 exact
  int c   = idx % 20;
  int t2  = idx / 20;
  int b   = t2 & 255;
  int sub = t2 >> 8;
  if (c >= C_) { dXr[idx] = 0.f; return; }
  int s = sub >> 1, j = sub & 1;
  float t_s = ts[s * B_], t_n = ts[(s + 1) * B_];
  float h = t_n - t_s;
  float xi, xn;
  if (c == 0) { xi = ts[s * B_ + b]; xn = ts[(s + 1) * B_ + b]; }
  else {
    xi = us[(size_t)s       * 4096 + b * 16 + (c - 1)];
    xn = us[(size_t)(s + 1) * 4096 + b * 16 + (c - 1)];
  }
  float mn = (xn - xi) / h;
  float mi;
  if (s == 0) mi = mn;
  else {
    float hp = t_s - ts[(s - 1) * B_];
    float xp = (c == 0) ? ts[(s - 1) * B_ + b]
                        : us[(size_t)(s - 1) * 4096 + b * 16 + (c - 1)];
    mi = (xi - xp) / hp;
  }
  float c2 = 3.f * (xn - xi) / (h * h) - (2.f * mi + mn) / h;
  float c3 = 2.f * (xi - xn) / (h * h * h) + (mi + mn) / (h * h);
  float u  = j ? 0.5f * h : 0.f;
  float dX = mi + 2.f * c2 * u + 3.f * c3 * u * u;
  dXr[idx] = dX * 0.5f * h;
}

// W2 A-frags per rank (validated): A[m=col(160: 8h x 20pad)][k=256].
__global__ void k_w2f(const float* __restrict__ W2,
                      u16* __restrict__ WH, u16* __restrict__ WL) {
  int idx = blockIdx.x * 256 + threadIdx.x;     // 1,310,720 (grid 5120)
  int e = idx & 7, lane = (idx >> 3) & 63, kt = (idx >> 9) & 7;
  int t = idx >> 12;
  int mt = t % 10, r = t / 10;
  int col = mt * 16 + (lane & 15);
  int hl = col / 20, c = col - hl * 20;
  int k = kt * 32 + 4 * (lane >> 4) + (e & 3) + 16 * (e >> 2);
  float v = (c < C_) ? W2[(size_t)k * (H_ * C_) + (r * 8 + hl) * C_ + c] : 0.f;
  u16 hi, lo; bsplit(v, hi, lo);
  WH[idx] = hi; WL[idx] = lo;
}

// W1 A-frags (validated): A[m=ho(256)][k=h_in(256)], [16 mtg][8 kt][64][8].
__global__ void k_w1f(const float* __restrict__ W1,
                      u16* __restrict__ WH, u16* __restrict__ WL) {
  int idx = blockIdx.x * 256 + threadIdx.x;     // 65536 (grid 256)
  int e = idx & 7, lane = (idx >> 3) & 63, kt = (idx >> 9) & 7, mtg = idx >> 12;
  int m = mtg * 16 + (lane & 15);
  int k = kt * 32 + 4 * (lane >> 4) + (e & 3) + 16 * (e >> 2);
  float v = W1[k * 256 + m];
  u16 hi, lo; bsplit(v, hi, lo);
  WH[idx] = hi; WL[idx] = lo;
}

// dec_W A-frags (validated): A[m=y(16)][k=h(256)].
__global__ void k_def(const float* __restrict__ decW,
                      u16* __restrict__ DH, u16* __restrict__ DL) {
  int idx = blockIdx.x * 256 + threadIdx.x;     // 4096 (grid 16)
  int e = idx & 7, lane = (idx >> 3) & 63, kt = idx >> 9;
  int y = lane & 15;
  int k = kt * 32 + 4 * (lane >> 4) + (e & 3) + 16 * (e >> 2);
  float v = decW[k * 16 + y];
  u16 hi, lo; bsplit(v, hi, lo);
  DH[idx] = hi; DL[idx] = lo;
}

// z0 frags (buf0): [16 grp][8 kt][64][8], z0[h][b] = enc_b[h].
__global__ void k_initF(const float* __restrict__ enc_b,
                        u16* __restrict__ ZH, u16* __restrict__ ZL) {
  int idx = blockIdx.x * 256 + threadIdx.x;     // 65536 (grid 256)
  int e = idx & 7, lane = (idx >> 3) & 63;
  int kt = (idx >> 9) & 7;
  int h = kt * 32 + 4 * (lane >> 4) + (e & 3) + 16 * (e >> 2);
  float v = enc_b[h];
  u16 hi, lo; bsplit(v, hi, lo);
  ZH[idx] = hi; ZL[idx] = lo;
}

// zero flags through the coherent point (every launch, stream-ordered)
__global__ void k_flg0(u32* f) {
  u32 z = 0;
  st1g(f + threadIdx.x, z);                     // 512 = 16 grp x 32 rank
}

// ---------------------------------------------------------------------------
// Persistent kernel: 256 blocks, 1/CU. Pair p = blk>>5 serves TWO groups
// (g0=2p, g1=2p+1; 16-b slabs), same rank (blk&31) in both -> same W2/W1
// rows. Software pipeline: role X's gather+flag-RT overlaps role Y's compute.
#define POLL_GRP(FLGP, SVAL)                                                   \
  {                                                                            \
    if (kq == 0) {                                                             \
      u32 guard_ = 0;                                                          \
      for (;;) {                                                               \
        u32 v_ = ld1g((FLGP) + (lane & 31));                                   \
        if (__all((int)(v_ >= (u32)(SVAL)))) break;                            \
        __builtin_amdgcn_s_sleep(1);                                           \
        if (++guard_ > (1u << 17)) break;                                      \
      }                                                                        \
    }                                                                          \
    __syncthreads();                                                           \
  }

#define ISSUE_Z(RV, GRP, SUBV)                                                 \
  {                                                                            \
    const f32x4* zh_ = (const f32x4*)(wsb + OFF_ZFH +                          \
        ((size_t)(((SUBV) & 1) * NGRP + (GRP))) * 8192);                       \
    const f32x4* zl_ = (const f32x4*)(wsb + OFF_ZFL +                          \
        ((size_t)(((SUBV) & 1) * NGRP + (GRP))) * 8192);                       \
    ld4c_nw(RV, zh_ + f0, zh_ + f1, zl_ + f0, zl_ + f1);                       \
  }

#define STAGE_Z(RV)                                                            \
  {                                                                            \
    wt4(RV);                                                                   \
    ((f32x4*)smem)[f0] = RV[0]; ((f32x4*)smem)[f1] = RV[1];                    \
    ((f32x4*)(smem + 8192))[f0] = RV[2]; ((f32x4*)(smem + 8192))[f1] = RV[3];  \
    __syncthreads();                                                           \
  }

#define DECODE_ROLE(GRP, SUBV)                                                 \
  {                                                                            \
    const bf16x8* zHl_ = (const bf16x8*)smem;                                  \
    const bf16x8* zLl_ = (const bf16x8*)(smem + 8192);                         \
    f32x4* red4_ = (f32x4*)(smem + 16384);                                     \
    f32x4 ad = (f32x4){0.f, 0.f, 0.f, 0.f};                                    \
    _Pragma("unroll")                                                          \
    for (int ktl = 0; ktl < 2; ++ktl) {                                        \
      int kt = kq * 2 + ktl;                                                   \
      bf16x8 dh = DHg[kt * 64 + lane], dl = DLg[kt * 64 + lane];               \
      bf16x8 zh = zHl_[kt * 64 + lane], zl = zLl_[kt * 64 + lane];             \
      ad = __builtin_amdgcn_mfma_f32_16x16x32_bf16(dh, zh, ad, 0, 0, 0);       \
      ad = __builtin_amdgcn_mfma_f32_16x16x32_bf16(dh, zl, ad, 0, 0, 0);       \
      ad = __builtin_amdgcn_mfma_f32_16x16x32_bf16(dl, zh, ad, 0, 0, 0);       \
    }                                                                          \
    if (kq) red4_[(kq - 1) * 64 + lane] = ad;                                  \
    __syncthreads();                                                           \
    if (kq == 0 && rank == 0) {                                                \
      _Pragma("unroll")                                                        \
      for (int q = 0; q < 3; ++q) ad += red4_[q * 64 + lane];                  \
      float4 q0;                                                               \
      q0.x = ad[0] + dec_b[4 * gg + 0]; q0.y = ad[1] + dec_b[4 * gg + 1];      \
      q0.z = ad[2] + dec_b[4 * gg + 2]; q0.w = ad[3] + dec_b[4 * gg + 3];      \
      *(float4*)(out + (size_t)((SUBV) >> 1) * 4096 +                          \
                 ((GRP) * 16 + c16) * 16 + 4 * gg) = q0;                       \
    }                                                                          \
    __syncthreads();                                                           \
  }

#define COMPUTE_ROLE(GRP, ZREG, FLGP, SUBV)                                    \
  {                                                                            \
    const bf16x8* zHl_ = (const bf16x8*)smem;                                  \
    const bf16x8* zLl_ = (const bf16x8*)(smem + 8192);                         \
    f32x4* red4_ = (f32x4*)(smem + 16384);                                     \
    f32x4 aa[4];                                                               \
    _Pragma("unroll")                                                          \
    for (int mm = 0; mm < 4; ++mm) aa[mm] = (f32x4){0.f, 0.f, 0.f, 0.f};       \
    _Pragma("unroll")                                                          \
    for (int kt = 0; kt < 8; ++kt) {                                           \
      bf16x8 zh = zHl_[kt * 64 + lane], zl = zLl_[kt * 64 + lane];             \
      _Pragma("unroll")                                                        \
      for (int mm = 0; mm < 4; ++mm) {                                         \
        bf16x8 wl = W1Lg[((4 * kq + mm) * 8 + kt) * 64 + lane];                \
        aa[mm] = __builtin_amdgcn_mfma_f32_16x16x32_bf16(w1hi[mm][kt], zh, aa[mm], 0, 0, 0); \
        aa[mm] = __builtin_amdgcn_mfma_f32_16x16x32_bf16(w1hi[mm][kt], zl, aa[mm], 0, 0, 0); \
        aa[mm] = __builtin_amdgcn_mfma_f32_16x16x32_bf16(wl, zh, aa[mm], 0, 0, 0); \
      }                                                                        \
    }                                                                          \
    bf16x8 hH[2], hL[2];                                                       \
    _Pragma("unroll")                                                          \
    for (int mm = 0; mm < 4; ++mm)                                             \
      _Pragma("unroll")                                                        \
      for (int r = 0; r < 4; ++r) {                                            \
        float v = aa[mm][r] + b1L[kq * 64 + mm * 16 + 4 * gg + r];             \
        v = fmaxf(v, 0.f);                                                     \
        u16 hi, lo; bsplit(v, hi, lo);                                         \
        hH[mm >> 1][r + 4 * (mm & 1)] = (short)hi;                             \
        hL[mm >> 1][r + 4 * (mm & 1)] = (short)lo;                             \
      }                                                                        \
    f32x4 ab[10];                                                              \
    _Pragma("unroll")                                                          \
    for (int mt = 0; mt < 10; ++mt) ab[mt] = (f32x4){0.f, 0.f, 0.f, 0.f};      \
    _Pragma("unroll")                                                          \
    for (int ktl = 0; ktl < 2; ++ktl)                                          \
      _Pragma("unroll")                                                        \
      for (int mt = 0; mt < 10; ++mt) {                                        \
        ab[mt] = __builtin_amdgcn_mfma_f32_16x16x32_bf16(wHi[ktl][mt], hH[ktl], ab[mt], 0, 0, 0); \
        ab[mt] = __builtin_amdgcn_mfma_f32_16x16x32_bf16(wHi[ktl][mt], hL[ktl], ab[mt], 0, 0, 0); \
        ab[mt] = __builtin_amdgcn_mfma_f32_16x16x32_bf16(wLo[ktl][mt], hH[ktl], ab[mt], 0, 0, 0); \
      }                                                                        \
    _Pragma("unroll")                                                          \
    for (int mt = 0; mt < 10; ++mt)                                            \
      red4_[(kq * 10 + mt) * 64 + lane] = ab[mt];                              \
    __syncthreads();                                                           \
    if (kq == 0) {                                                             \
      float ph[8] = {0.f,0.f,0.f,0.f,0.f,0.f,0.f,0.f};                         \
      _Pragma("unroll")                                                        \
      for (int mt = 0; mt < 10; ++mt) {                                        \
        f32x4 s = red4_[(0 * 10 + mt) * 64 + lane]                             \
                + red4_[(1 * 10 + mt) * 64 + lane]                             \
                + red4_[(2 * 10 + mt) * 64 + lane]                             \
                + red4_[(3 * 10 + mt) * 64 + lane];                            \
        int col0 = mt * 16 + 4 * gg;                                           \
        int hl_  = col0 / 20;                                                  \
        int c0   = col0 - hl_ * 20;                                            \
        float4 b2v = *(const float4*)&b2L[col0];                               \
        float4 dxv = *(const float4*)(dXr +                                    \
            ((size_t)(SUBV) * 256 + (GRP) * 16 + c16) * 20 + c0);              \
        float t0 = fast_tanh(s[0] + b2v.x);                                    \
        float t1 = fast_tanh(s[1] + b2v.y);                                    \
        float t2 = fast_tanh(s[2] + b2v.z);                                    \
        float t3 = fast_tanh(s[3] + b2v.w);                                    \
        float contrib = fmaf(t0, dxv.x, fmaf(t1, dxv.y, fmaf(t2, dxv.z, t3 * dxv.w))); \
        _Pragma("unroll")                                                      \
        for (int hh = 0; hh < 8; ++hh)                                         \
          ph[hh] += (hl_ == hh) ? contrib : 0.f;                               \
      }                                                                        \
      _Pragma("unroll")                                                        \
      for (int hh = 0; hh < 8; ++hh) {                                         \
        float v = ph[hh];                                                      \
        v += __shfl_xor(v, 16);                                                \
        v += __shfl_xor(v, 32);                                                \
        ZREG[hh] += v;                                                         \
      }                                                                        \
      if (gg == 0) {                                                           \
        u16* zdH = (u16*)(wsb + OFF_ZFH) +                                     \
            ((size_t)(((SUBV) + 1) & 1) * NGRP + (GRP)) * 4096;                \
        u16* zdL = (u16*)(wsb + OFF_ZFL) +                                     \
            ((size_t)(((SUBV) + 1) & 1) * NGRP + (GRP)) * 4096;                \
        _Pragma("unroll")                                                      \
        for (int q = 0; q < 2; ++q) {                                          \
          u16 h0,l0,h1,l1,h2,l2,h3,l3;                                         \
          bsplit(ZREG[q*4+0], h0, l0); bsplit(ZREG[q*4+1], h1, l1);            \
          bsplit(ZREG[q*4+2], h2, l2); bsplit(ZREG[q*4+3], h3, l3);            \
          u32x2 vh, vl;                                                        \
          vh[0] = (u32)h0 | ((u32)h1 << 16); vh[1] = (u32)h2 | ((u32)h3 << 16);\
          vl[0] = (u32)l0 | ((u32)l1 << 16); vl[1] = (u32)l2 | ((u32)l3 << 16);\
          int fi = (kt2s * 64 + lpb + 16 * q) * 8 + ebase;                     \
          st8b(zdH + fi, vh);                                                  \
          st8b(zdL + fi, vl);                                                  \
        }                                                                      \
      }                                                                        \
    }                                                                          \
    asm volatile("s_waitcnt vmcnt(0)" ::: "memory");                           \
    __syncthreads();                                                           \
    if (tid == 0) st1g((FLGP) + rank, (u32)((SUBV) + 1));                      \
  }

__global__ __launch_bounds__(256, 1)
void k_ode7(char* __restrict__ wsb, const float* __restrict__ enc_b,
            const float* __restrict__ f_b1, const float* __restrict__ f_b2,
            const float* __restrict__ dec_b, float* __restrict__ out) {
  const int tid = threadIdx.x, lane = tid & 63, kq = tid >> 6;
  const int pr = blockIdx.x >> 5, rank = blockIdx.x & 31;
  const int g0 = 2 * pr, g1 = 2 * pr + 1;
  const int gg = lane >> 4, c16 = lane & 15;

  // LDS: zstage hi [0,8K) lo [8K,16K) | red4 40K [16K,56K) | b1L | b2L
  __shared__ __align__(16) char smem[59008];
  float* b1L = (float*)(smem + 57344);          // 256 f32
  float* b2L = (float*)(smem + 58368);          // 160 f32

  b1L[tid] = f_b1[tid];
  if (tid < 160) { int hl = tid / 20, c = tid - hl * 20;
                   b2L[tid] = (c < C_) ? f_b2[(rank * 8 + hl) * C_ + c] : 0.f; }

  const bf16x8* W2Hg = (const bf16x8*)(wsb + OFF_W2H);
  const bf16x8* W2Lg = (const bf16x8*)(wsb + OFF_W2L);
  const bf16x8* W1Hg = (const bf16x8*)(wsb + OFF_W1H);
  const bf16x8* W1Lg = (const bf16x8*)(wsb + OFF_W1L);
  const bf16x8* DHg  = (const bf16x8*)(wsb + OFF_DEH);
  const bf16x8* DLg  = (const bf16x8*)(wsb + OFF_DEL);
  const float*  dXr  = (const float*)(wsb + OFF_DXR);
  u32* flgA = (u32*)(wsb + OFF_FLG) + g0 * 32;
  u32* flgB = (u32*)(wsb + OFF_FLG) + g1 * 32;

  // persistent frags: W2 hi+lo (160 VGPR) + W1-hi (128 VGPR); W1-lo streamed.
  bf16x8 wHi[2][10], wLo[2][10];
  #pragma unroll
  for (int ktl = 0; ktl < 2; ++ktl)
    #pragma unroll
    for (int mt = 0; mt < 10; ++mt) {
      wHi[ktl][mt] = W2Hg[((rank * 10 + mt) * 8 + kq * 2 + ktl) * 64 + lane];
      wLo[ktl][mt] = W2Lg[((rank * 10 + mt) * 8 + kq * 2 + ktl) * 64 + lane];
    }
  bf16x8 w1hi[4][8];
  #pragma unroll
  for (int mm = 0; mm < 4; ++mm)
    #pragma unroll
    for (int kt = 0; kt < 8; ++kt)
      w1hi[mm][kt] = W1Hg[((4 * kq + mm) * 8 + kt) * 64 + lane];

  // producer-side store geometry (R9/R10-validated quad mapping)
  const int kt2s = rank >> 2;
  const int r8   = (rank & 3) * 8;
  const int ebase = (r8 & 16) ? 4 : 0;
  const int lpb   = c16 + ((r8 & 8) ? 32 : 0);

  // fp32 master z per role (wave 0)
  float zA[8], zB[8];
  if (kq == 0)
    #pragma unroll
    for (int hh = 0; hh < 8; ++hh) { zA[hh] = enc_b[rank * 8 + hh]; zB[hh] = zA[hh]; }

  const int f0 = (2 * kq + 0) * 64 + lane;
  const int f1 = (2 * kq + 1) * 64 + lane;
  f32x4 rA[4], rB[4];

  __syncthreads();

  ISSUE_Z(rA, g0, 0);                            // buf0 init'd; flags pass @0

  for (int sub = 0; ; ++sub) {
    // ===== HALF A: role g0 @ sub =====
    STAGE_Z(rA);
    if (sub < NSUB) {
      POLL_GRP(flgB, sub);
      ISSUE_Z(rB, g1, sub);                      // overlaps decode+phaseA below
      if ((sub & 1) == 0) DECODE_ROLE(g0, sub);
      COMPUTE_ROLE(g0, zA, flgA, sub);
    } else {
      DECODE_ROLE(g0, sub);                      // sub == 254 (even): row 127
      POLL_GRP(flgB, sub);
      ISSUE_Z(rB, g1, sub);
      STAGE_Z(rB);
      DECODE_ROLE(g1, sub);
      break;
    }

    // ===== HALF B: role g1 @ sub =====
    STAGE_Z(rB);
    POLL_GRP(flgA, sub + 1);
    ISSUE_Z(rA, g0, sub + 1);                    // overlaps decode+phaseA below
    if ((sub & 1) == 0) DECODE_ROLE(g1, sub);
    COMPUTE_ROLE(g1, zB, flgB, sub);
  }
}

// ---------------------------------------------------------------------------
extern "C" void kernel_launch(void* const* d_in, const int* in_sizes, int n_in,
                              void* d_out, int out_size, void* d_ws, size_t ws_size,
                              hipStream_t stream) {
  const float* ts    = (const float*)d_in[0];
  const float* us    = (const float*)d_in[1];
  const float* enc_b = (const float*)d_in[5];
  const float* dec_W = (const float*)d_in[6];
  const float* dec_b = (const float*)d_in[7];
  const float* f_W1  = (const float*)d_in[8];
  const float* f_b1  = (const float*)d_in[9];
  const float* f_W2  = (const float*)d_in[10];
  const float* f_b2  = (const float*)d_in[11];
  float* out = (float*)d_out;
  char* wsb = (char*)d_ws;

  k_dx   <<<5080, 256, 0, stream>>>(ts, us, (float*)(wsb + OFF_DXR));
  k_w2f  <<<5120, 256, 0, stream>>>(f_W2, (u16*)(wsb + OFF_W2H), (u16*)(wsb + OFF_W2L));
  k_w1f  <<<256, 256, 0, stream>>>(f_W1, (u16*)(wsb + OFF_W1H), (u16*)(wsb + OFF_W1L));
  k_def  <<<16, 256, 0, stream>>>(dec_W, (u16*)(wsb + OFF_DEH), (u16*)(wsb + OFF_DEL));
  k_initF<<<256, 256, 0, stream>>>(enc_b, (u16*)(wsb + OFF_ZFH), (u16*)(wsb + OFF_ZFL));
  k_flg0 <<<1, 512, 0, stream>>>((u32*)(wsb + OFF_FLG));

  k_ode7<<<256, 256, 0, stream>>>(wsb, enc_b, f_b1, f_b2, dec_b, out);
}

// Round 12
// 2941.214 us; speedup vs baseline: 732.6369x; 1.5010x over previous
//
#include <hip/hip_runtime.h>
#include <hip/hip_bf16.h>
#include <cmath>

// L=128, B=256, H=256, C=17, Y=16, N_SUB=2
#define L_   128
#define B_   256
#define H_   256
#define C_   17
#define Y_   16
#define NSUB 254
#define NGRP 16          // groups: b-slabs of 16
#define RNK  16          // ranks per group: 16 h each

typedef short bf16x8 __attribute__((ext_vector_type(8)));
typedef float f32x4  __attribute__((ext_vector_type(4)));
typedef unsigned short u16;
typedef unsigned int   u32;

// ---- workspace byte offsets ------------------------------------------------
#define OFF_DXR  0u           // [254][256 b][20 c] f32              5,201,920
#define OFF_W2H  5201920u     // [16 r * 20 mt][8 kt][64][8] u16     2,621,440
#define OFF_W2L  7823360u
#define OFF_W1H  10444800u    // [16 mtg][8 kt][64][8] u16             131,072
#define OFF_W1L  10575872u
#define OFF_DEH  10706944u    // [8 kt][64][8] u16                       8,192
#define OFF_DEL  10715136u
#define OFF_ZFH  10723328u    // [2 buf][16 grp][8 kt][64][8] u16      262,144
#define OFF_ZFL  10985472u
#define OFF_ZM   11247616u    // [16 grp][16 r][16 h][16 b] f32        262,144

__device__ __forceinline__ float fast_tanh(float x) {
  float e = __expf(2.0f * x);
  return 1.0f - __fdividef(2.0f, e + 1.0f);
}

__device__ __forceinline__ void bsplit(float x, u16& hi, u16& lo) {
  __hip_bfloat16 h = __float2bfloat16(x);
  float hf = __bfloat162float(h);
  __hip_bfloat16 l = __float2bfloat16(x - hf);
  hi = *(u16*)&h;
  lo = *(u16*)&l;
}

// ---------------------------------------------------------------------------
// dXr[sub][b][c(20 pad)] = dX * (h/2)          (validated R4-R11)
__global__ void k_dx(const float* __restrict__ ts, const float* __restrict__ us,
                     float* __restrict__ dXr) {
  int idx = blockIdx.x * 256 + threadIdx.x;     // 1,300,480 exact
  int c   = idx % 20;
  int t2  = idx / 20;
  int b   = t2 & 255;
  int sub = t2 >> 8;
  if (c >= C_) { dXr[idx] = 0.f; return; }
  int s = sub >> 1, j = sub & 1;
  float t_s = ts[s * B_], t_n = ts[(s + 1) * B_];
  float h = t_n - t_s;
  float xi, xn;
  if (c == 0) { xi = ts[s * B_ + b]; xn = ts[(s + 1) * B_ + b]; }
  else {
    xi = us[(size_t)s       * 4096 + b * 16 + (c - 1)];
    xn = us[(size_t)(s + 1) * 4096 + b * 16 + (c - 1)];
  }
  float mn = (xn - xi) / h;
  float mi;
  if (s == 0) mi = mn;
  else {
    float hp = t_s - ts[(s - 1) * B_];
    float xp = (c == 0) ? ts[(s - 1) * B_ + b]
                        : us[(size_t)(s - 1) * 4096 + b * 16 + (c - 1)];
    mi = (xi - xp) / hp;
  }
  float c2 = 3.f * (xn - xi) / (h * h) - (2.f * mi + mn) / h;
  float c3 = 2.f * (xi - xn) / (h * h * h) + (mi + mn) / (h * h);
  float u  = j ? 0.5f * h : 0.f;
  float dX = mi + 2.f * c2 * u + 3.f * c3 * u * u;
  dXr[idx] = dX * 0.5f * h;
}

// ---------------------------------------------------------------------------
// W2 A-frags: per (rank, mt) slab t = rank*20+mt; A[m=col(320: 16h x 20pad)][k=256].
__global__ void k_w2f(const float* __restrict__ W2,
                      u16* __restrict__ WH, u16* __restrict__ WL) {
  int idx = blockIdx.x * 256 + threadIdx.x;     // 1,310,720 (grid 5120)
  int e = idx & 7, lane = (idx >> 3) & 63, kt = (idx >> 9) & 7;
  int t = idx >> 12;
  int mt = t % 20, r = t / 20;
  int col = mt * 16 + (lane & 15);              // 0..319
  int hl = col / 20, c = col - hl * 20;
  int k = kt * 32 + 4 * (lane >> 4) + (e & 3) + 16 * (e >> 2);
  float v = (c < C_) ? W2[(size_t)k * (H_ * C_) + (r * 16 + hl) * C_ + c] : 0.f;
  u16 hi, lo; bsplit(v, hi, lo);
  WH[idx] = hi; WL[idx] = lo;
}

// W1 A-frags (validated): A[m=ho(256)][k=h_in(256)], [16 mtg][8 kt][64][8].
__global__ void k_w1f(const float* __restrict__ W1,
                      u16* __restrict__ WH, u16* __restrict__ WL) {
  int idx = blockIdx.x * 256 + threadIdx.x;     // 65536 (grid 256)
  int e = idx & 7, lane = (idx >> 3) & 63, kt = (idx >> 9) & 7, mtg = idx >> 12;
  int m = mtg * 16 + (lane & 15);
  int k = kt * 32 + 4 * (lane >> 4) + (e & 3) + 16 * (e >> 2);
  float v = W1[k * 256 + m];
  u16 hi, lo; bsplit(v, hi, lo);
  WH[idx] = hi; WL[idx] = lo;
}

// dec_W A-frags (validated): A[m=y(16)][k=h(256)].
__global__ void k_def(const float* __restrict__ decW,
                      u16* __restrict__ DH, u16* __restrict__ DL) {
  int idx = blockIdx.x * 256 + threadIdx.x;     // 4096 (grid 16)
  int e = idx & 7, lane = (idx >> 3) & 63, kt = idx >> 9;
  int y = lane & 15;
  int k = kt * 32 + 4 * (lane >> 4) + (e & 3) + 16 * (e >> 2);
  float v = decW[k * 16 + y];
  u16 hi, lo; bsplit(v, hi, lo);
  DH[idx] = hi; DL[idx] = lo;
}

// z0 frags (buf0): [16 grp][8 kt][64][8], z0[h][b] = enc_b[h].   (validated)
__global__ void k_initF(const float* __restrict__ enc_b,
                        u16* __restrict__ ZH, u16* __restrict__ ZL) {
  int idx = blockIdx.x * 256 + threadIdx.x;     // 65536 (grid 256)
  int e = idx & 7, lane = (idx >> 3) & 63;
  int kt = (idx >> 9) & 7;
  int h = kt * 32 + 4 * (lane >> 4) + (e & 3) + 16 * (e >> 2);
  float v = enc_b[h];
  u16 hi, lo; bsplit(v, hi, lo);
  ZH[idx] = hi; ZL[idx] = lo;
}

// zM[grp][rank][h_loc][b] = enc_b[rank*16 + h_loc]
__global__ void k_zm0(const float* __restrict__ enc_b, float* __restrict__ zM) {
  int idx = blockIdx.x * 256 + threadIdx.x;     // 65536 (grid 256)
  zM[idx] = enc_b[(idx >> 4) & 255];
}

// ---------------------------------------------------------------------------
// One substep. 256 independent blocks = 16 groups (16 b) x 16 ranks (16 h).
// Cross-substep coherence = kernel dispatch boundary (HW release/acquire).
// Flow: stage zF -> (rank0, even sub) decode -> phase A (wave kq computes its
// ho-quarter; reg repack) -> LDS hdn exchange -> phase B (wave kq owns 5 mt =
// 4 h, full K; no cross-wave reduce) -> epilogue -> zM + zF frag stores.
__global__ __launch_bounds__(256, 1)
void k_step(char* __restrict__ wsb, const float* __restrict__ f_b1,
            const float* __restrict__ f_b2, const float* __restrict__ dec_b,
            float* __restrict__ out, int sub) {
  const int tid = threadIdx.x, lane = tid & 63, kq = tid >> 6;
  const int grp = blockIdx.x >> 4, rank = blockIdx.x & 15;
  const int gg = lane >> 4, c16 = lane & 15;

  if (sub == NSUB && rank != 0) return;         // final launch: decode only

  // LDS: zs hi/lo 16K | hx hi/lo 16K | red 3K | b1L 1K | b2L 1.25K
  __shared__ __align__(16) char smem[38400];
  u16* zsH = (u16*)smem;
  u16* zsL = (u16*)(smem + 8192);
  u16* hxH = (u16*)(smem + 16384);
  u16* hxL = (u16*)(smem + 24576);
  f32x4* red4 = (f32x4*)(smem + 32768);
  float* b1L  = (float*)(smem + 35840);
  float* b2L  = (float*)(smem + 36864);         // 320 f32

  b1L[tid] = f_b1[tid];
  for (int i = tid; i < 320; i += 256) {
    int hl = i / 20, c = i - hl * 20;
    b2L[i] = (c < C_) ? f_b2[(rank * 16 + hl) * C_ + c] : 0.f;
  }

  const bf16x8* W2Hg = (const bf16x8*)(wsb + OFF_W2H);
  const bf16x8* W2Lg = (const bf16x8*)(wsb + OFF_W2L);
  const bf16x8* W1Hg = (const bf16x8*)(wsb + OFF_W1H);
  const bf16x8* W1Lg = (const bf16x8*)(wsb + OFF_W1L);
  const bf16x8* DHg  = (const bf16x8*)(wsb + OFF_DEH);
  const bf16x8* DLg  = (const bf16x8*)(wsb + OFF_DEL);
  const float*  dXr  = (const float*)(wsb + OFF_DXR);
  float* zM = (float*)(wsb + OFF_ZM) + ((size_t)(grp * 16 + rank)) * 256;

  // fp32 master z for this wave's 4 h (lanes gg==0 hold b=c16)
  float zm[4];
  #pragma unroll
  for (int hh = 0; hh < 4; ++hh)
    zm[hh] = zM[(4 * kq + hh) * 16 + c16];

  // ---- stage this group's z frags (hi+lo) into LDS ----
  {
    const f32x4* gzH = (const f32x4*)(wsb + OFF_ZFH +
                         ((size_t)(sub & 1) * NGRP + grp) * 8192);
    const f32x4* gzL = (const f32x4*)(wsb + OFF_ZFL +
                         ((size_t)(sub & 1) * NGRP + grp) * 8192);
    ((f32x4*)zsH)[tid]       = gzH[tid];
    ((f32x4*)zsH)[tid + 256] = gzH[tid + 256];
    ((f32x4*)zsL)[tid]       = gzL[tid];
    ((f32x4*)zsL)[tid + 256] = gzL[tid + 256];
  }
  __syncthreads();

  // ---- decode (even subs, rank 0): out[sub/2] = z @ decW + dec_b ----
  if (((sub & 1) == 0) && rank == 0) {
    f32x4 ad = (f32x4){0.f, 0.f, 0.f, 0.f};
    #pragma unroll
    for (int ktl = 0; ktl < 2; ++ktl) {
      int kt = kq * 2 + ktl;
      bf16x8 dh = DHg[kt * 64 + lane], dl = DLg[kt * 64 + lane];
      bf16x8 zh = ((const bf16x8*)zsH)[kt * 64 + lane];
      bf16x8 zl = ((const bf16x8*)zsL)[kt * 64 + lane];
      ad = __builtin_amdgcn_mfma_f32_16x16x32_bf16(dh, zh, ad, 0, 0, 0);
      ad = __builtin_amdgcn_mfma_f32_16x16x32_bf16(dh, zl, ad, 0, 0, 0);
      ad = __builtin_amdgcn_mfma_f32_16x16x32_bf16(dl, zh, ad, 0, 0, 0);
    }
    if (kq) red4[(kq - 1) * 64 + lane] = ad;
    __syncthreads();
    if (kq == 0) {
      #pragma unroll
      for (int q = 0; q < 3; ++q) ad += red4[q * 64 + lane];
      float4 q0;
      q0.x = ad[0] + dec_b[4 * gg + 0]; q0.y = ad[1] + dec_b[4 * gg + 1];
      q0.z = ad[2] + dec_b[4 * gg + 2]; q0.w = ad[3] + dec_b[4 * gg + 3];
      *(float4*)(out + (size_t)(sub >> 1) * 4096 +
                 (grp * 16 + c16) * 16 + 4 * gg) = q0;
    }
    __syncthreads();
  }
  if (sub == NSUB) return;

  // ---- phase A: wave kq computes hdn rows ho in [64kq, 64kq+64) ----
  f32x4 aa[4];
  #pragma unroll
  for (int mm = 0; mm < 4; ++mm) aa[mm] = (f32x4){0.f, 0.f, 0.f, 0.f};
  #pragma unroll
  for (int kt = 0; kt < 8; ++kt) {
    bf16x8 zh = ((const bf16x8*)zsH)[kt * 64 + lane];
    bf16x8 zl = ((const bf16x8*)zsL)[kt * 64 + lane];
    #pragma unroll
    for (int mm = 0; mm < 4; ++mm) {
      bf16x8 wh = W1Hg[((4 * kq + mm) * 8 + kt) * 64 + lane];
      bf16x8 wl = W1Lg[((4 * kq + mm) * 8 + kt) * 64 + lane];
      aa[mm] = __builtin_amdgcn_mfma_f32_16x16x32_bf16(wh, zh, aa[mm], 0, 0, 0);
      aa[mm] = __builtin_amdgcn_mfma_f32_16x16x32_bf16(wh, zl, aa[mm], 0, 0, 0);
      aa[mm] = __builtin_amdgcn_mfma_f32_16x16x32_bf16(wl, zh, aa[mm], 0, 0, 0);
    }
  }

  // ---- reg repack (validated) + LDS hdn exchange: kt2 = 2kq + (mm>>1) ----
  {
    bf16x8 hH[2], hL[2];
    #pragma unroll
    for (int mm = 0; mm < 4; ++mm)
      #pragma unroll
      for (int r = 0; r < 4; ++r) {
        float v = aa[mm][r] + b1L[kq * 64 + mm * 16 + 4 * gg + r];
        v = fmaxf(v, 0.f);
        u16 hi, lo; bsplit(v, hi, lo);
        hH[mm >> 1][r + 4 * (mm & 1)] = (short)hi;
        hL[mm >> 1][r + 4 * (mm & 1)] = (short)lo;
      }
    ((bf16x8*)hxH)[(2 * kq + 0) * 64 + lane] = hH[0];
    ((bf16x8*)hxH)[(2 * kq + 1) * 64 + lane] = hH[1];
    ((bf16x8*)hxL)[(2 * kq + 0) * 64 + lane] = hL[0];
    ((bf16x8*)hxL)[(2 * kq + 1) * 64 + lane] = hL[1];
  }
  __syncthreads();

  // ---- phase B: wave kq owns mt in [5kq, 5kq+5) (= 4 h), full K=256 ----
  f32x4 ab[5];
  #pragma unroll
  for (int ml = 0; ml < 5; ++ml) ab[ml] = (f32x4){0.f, 0.f, 0.f, 0.f};
  #pragma unroll
  for (int kt = 0; kt < 8; ++kt) {
    bf16x8 hh = ((const bf16x8*)hxH)[kt * 64 + lane];
    bf16x8 hl = ((const bf16x8*)hxL)[kt * 64 + lane];
    #pragma unroll
    for (int ml = 0; ml < 5; ++ml) {
      bf16x8 wh = W2Hg[(((rank * 20 + kq * 5 + ml) * 8) + kt) * 64 + lane];
      bf16x8 wl = W2Lg[(((rank * 20 + kq * 5 + ml) * 8) + kt) * 64 + lane];
      ab[ml] = __builtin_amdgcn_mfma_f32_16x16x32_bf16(wh, hh, ab[ml], 0, 0, 0);
      ab[ml] = __builtin_amdgcn_mfma_f32_16x16x32_bf16(wh, hl, ab[ml], 0, 0, 0);
      ab[ml] = __builtin_amdgcn_mfma_f32_16x16x32_bf16(wl, hh, ab[ml], 0, 0, 0);
    }
  }

  // ---- epilogue (per wave, 4 h): tanh, c-contract, z update, frag store ----
  {
    float ph[4] = {0.f, 0.f, 0.f, 0.f};
    #pragma unroll
    for (int ml = 0; ml < 5; ++ml) {
      int col0 = (kq * 5 + ml) * 16 + 4 * gg;
      int hl_  = col0 / 20;                     // in [4kq, 4kq+4)
      int c0   = col0 - hl_ * 20;
      float4 b2v = *(const float4*)&b2L[col0];
      float4 dxv = *(const float4*)(dXr +
          ((size_t)sub * 256 + grp * 16 + c16) * 20 + c0);
      float t0 = fast_tanh(ab[ml][0] + b2v.x);
      float t1 = fast_tanh(ab[ml][1] + b2v.y);
      float t2 = fast_tanh(ab[ml][2] + b2v.z);
      float t3 = fast_tanh(ab[ml][3] + b2v.w);
      float contrib = fmaf(t0, dxv.x, fmaf(t1, dxv.y, fmaf(t2, dxv.z, t3 * dxv.w)));
      int hrel = hl_ - 4 * kq;
      #pragma unroll
      for (int hh = 0; hh < 4; ++hh)
        ph[hh] += (hrel == hh) ? contrib : 0.f;
    }
    #pragma unroll
    for (int hh = 0; hh < 4; ++hh) {
      float v = ph[hh];
      v += __shfl_xor(v, 16);
      v += __shfl_xor(v, 32);
      zm[hh] += v;
    }
    if (gg == 0) {
      // zM master store
      #pragma unroll
      for (int hh = 0; hh < 4; ++hh)
        zM[(4 * kq + hh) * 16 + c16] = zm[hh];
      // zF frag quad store (validated geometry): hg0 = rank*16 + 4kq
      int hg0 = rank * 16 + 4 * kq;
      int ktf = hg0 >> 5, kl0 = hg0 & 31;
      int lp  = c16 + 16 * ((kl0 >> 2) & 3);
      int e0  = 4 * ((kl0 >> 4) & 1);
      int fi  = (ktf * 64 + lp) * 8 + e0;       // u16 units
      u16* zdH = (u16*)(wsb + OFF_ZFH) +
                 ((size_t)((sub + 1) & 1) * NGRP + grp) * 4096;
      u16* zdL = (u16*)(wsb + OFF_ZFL) +
                 ((size_t)((sub + 1) & 1) * NGRP + grp) * 4096;
      ushort4 vh, vl;
      u16 h0, l0;
      bsplit(zm[0], h0, l0); vh.x = h0; vl.x = l0;
      bsplit(zm[1], h0, l0); vh.y = h0; vl.y = l0;
      bsplit(zm[2], h0, l0); vh.z = h0; vl.z = l0;
      bsplit(zm[3], h0, l0); vh.w = h0; vl.w = l0;
      *(ushort4*)(zdH + fi) = vh;
      *(ushort4*)(zdL + fi) = vl;
    }
  }
}

// ---------------------------------------------------------------------------
extern "C" void kernel_launch(void* const* d_in, const int* in_sizes, int n_in,
                              void* d_out, int out_size, void* d_ws, size_t ws_size,
                              hipStream_t stream) {
  const float* ts    = (const float*)d_in[0];
  const float* us    = (const float*)d_in[1];
  const float* enc_b = (const float*)d_in[5];
  const float* dec_W = (const float*)d_in[6];
  const float* dec_b = (const float*)d_in[7];
  const float* f_W1  = (const float*)d_in[8];
  const float* f_b1  = (const float*)d_in[9];
  const float* f_W2  = (const float*)d_in[10];
  const float* f_b2  = (const float*)d_in[11];
  float* out = (float*)d_out;
  char* wsb = (char*)d_ws;

  k_dx   <<<5080, 256, 0, stream>>>(ts, us, (float*)(wsb + OFF_DXR));
  k_w2f  <<<5120, 256, 0, stream>>>(f_W2, (u16*)(wsb + OFF_W2H), (u16*)(wsb + OFF_W2L));
  k_w1f  <<<256, 256, 0, stream>>>(f_W1, (u16*)(wsb + OFF_W1H), (u16*)(wsb + OFF_W1L));
  k_def  <<<16, 256, 0, stream>>>(dec_W, (u16*)(wsb + OFF_DEH), (u16*)(wsb + OFF_DEL));
  k_initF<<<256, 256, 0, stream>>>(enc_b, (u16*)(wsb + OFF_ZFH), (u16*)(wsb + OFF_ZFL));
  k_zm0  <<<256, 256, 0, stream>>>(enc_b, (float*)(wsb + OFF_ZM));

  for (int sub = 0; sub <= NSUB; ++sub)
    k_step<<<256, 256, 0, stream>>>(wsb, f_b1, f_b2, dec_b, out, sub);
}

// Round 13
// 2517.494 us; speedup vs baseline: 855.9472x; 1.1683x over previous
//
#include <hip/hip_runtime.h>
#include <hip/hip_bf16.h>
#include <cmath>

// L=128, B=256, H=256, C=17, Y=16, N_SUB=2
#define L_   128
#define B_   256
#define H_   256
#define C_   17
#define Y_   16
#define NSUB 254
#define NGRP 16          // groups: b-slabs of 16
#define RNK  16          // ranks per group: 16 h each

typedef short bf16x8 __attribute__((ext_vector_type(8)));
typedef float f32x4  __attribute__((ext_vector_type(4)));
typedef unsigned short u16;
typedef unsigned int   u32;

// ---- workspace byte offsets (identical to R12) -----------------------------
#define OFF_DXR  0u           // [254][256 b][20 c] f32              5,201,920
#define OFF_W2H  5201920u     // [16 r * 20 mt][8 kt][64][8] u16     2,621,440
#define OFF_W2L  7823360u
#define OFF_W1H  10444800u    // [16 mtg][8 kt][64][8] u16             131,072
#define OFF_W1L  10575872u
#define OFF_DEH  10706944u    // [8 kt][64][8] u16                       8,192
#define OFF_DEL  10715136u
#define OFF_ZFH  10723328u    // [2 buf][16 grp][8 kt][64][8] u16      262,144
#define OFF_ZFL  10985472u
#define OFF_ZM   11247616u    // [16 grp][16 r][16 h][16 b] f32        262,144

__device__ __forceinline__ float fast_tanh(float x) {
  float e = __expf(2.0f * x);
  return 1.0f - __fdividef(2.0f, e + 1.0f);
}

__device__ __forceinline__ void bsplit(float x, u16& hi, u16& lo) {
  __hip_bfloat16 h = __float2bfloat16(x);
  float hf = __bfloat162float(h);
  __hip_bfloat16 l = __float2bfloat16(x - hf);
  hi = *(u16*)&h;
  lo = *(u16*)&l;
}

// ---------------------------------------------------------------------------
// dXr[sub][b][c(20 pad)] = dX * (h/2)          (validated R4-R12)
__global__ void k_dx(const float* __restrict__ ts, const float* __restrict__ us,
                     float* __restrict__ dXr) {
  int idx = blockIdx.x * 256 + threadIdx.x;     // 1,300,480 exact
  int c   = idx % 20;
  int t2  = idx / 20;
  int b   = t2 & 255;
  int sub = t2 >> 8;
  if (c >= C_) { dXr[idx] = 0.f; return; }
  int s = sub >> 1, j = sub & 1;
  float t_s = ts[s * B_], t_n = ts[(s + 1) * B_];
  float h = t_n - t_s;
  float xi, xn;
  if (c == 0) { xi = ts[s * B_ + b]; xn = ts[(s + 1) * B_ + b]; }
  else {
    xi = us[(size_t)s       * 4096 + b * 16 + (c - 1)];
    xn = us[(size_t)(s + 1) * 4096 + b * 16 + (c - 1)];
  }
  float mn = (xn - xi) / h;
  float mi;
  if (s == 0) mi = mn;
  else {
    float hp = t_s - ts[(s - 1) * B_];
    float xp = (c == 0) ? ts[(s - 1) * B_ + b]
                        : us[(size_t)(s - 1) * 4096 + b * 16 + (c - 1)];
    mi = (xi - xp) / hp;
  }
  float c2 = 3.f * (xn - xi) / (h * h) - (2.f * mi + mn) / h;
  float c3 = 2.f * (xi - xn) / (h * h * h) + (mi + mn) / (h * h);
  float u  = j ? 0.5f * h : 0.f;
  float dX = mi + 2.f * c2 * u + 3.f * c3 * u * u;
  dXr[idx] = dX * 0.5f * h;
}

// ---------------------------------------------------------------------------
// W2 A-frags (validated R12): slab t = rank*20+mt; A[m=col(320)][k=256].
__global__ void k_w2f(const float* __restrict__ W2,
                      u16* __restrict__ WH, u16* __restrict__ WL) {
  int idx = blockIdx.x * 256 + threadIdx.x;     // 1,310,720 (grid 5120)
  int e = idx & 7, lane = (idx >> 3) & 63, kt = (idx >> 9) & 7;
  int t = idx >> 12;
  int mt = t % 20, r = t / 20;
  int col = mt * 16 + (lane & 15);              // 0..319
  int hl = col / 20, c = col - hl * 20;
  int k = kt * 32 + 4 * (lane >> 4) + (e & 3) + 16 * (e >> 2);
  float v = (c < C_) ? W2[(size_t)k * (H_ * C_) + (r * 16 + hl) * C_ + c] : 0.f;
  u16 hi, lo; bsplit(v, hi, lo);
  WH[idx] = hi; WL[idx] = lo;
}

// W1 A-frags (validated): A[m=ho(256)][k=h_in(256)], [16 mtg][8 kt][64][8].
__global__ void k_w1f(const float* __restrict__ W1,
                      u16* __restrict__ WH, u16* __restrict__ WL) {
  int idx = blockIdx.x * 256 + threadIdx.x;     // 65536 (grid 256)
  int e = idx & 7, lane = (idx >> 3) & 63, kt = (idx >> 9) & 7, mtg = idx >> 12;
  int m = mtg * 16 + (lane & 15);
  int k = kt * 32 + 4 * (lane >> 4) + (e & 3) + 16 * (e >> 2);
  float v = W1[k * 256 + m];
  u16 hi, lo; bsplit(v, hi, lo);
  WH[idx] = hi; WL[idx] = lo;
}

// dec_W A-frags (validated): A[m=y(16)][k=h(256)].
__global__ void k_def(const float* __restrict__ decW,
                      u16* __restrict__ DH, u16* __restrict__ DL) {
  int idx = blockIdx.x * 256 + threadIdx.x;     // 4096 (grid 16)
  int e = idx & 7, lane = (idx >> 3) & 63, kt = idx >> 9;
  int y = lane & 15;
  int k = kt * 32 + 4 * (lane >> 4) + (e & 3) + 16 * (e >> 2);
  float v = decW[k * 16 + y];
  u16 hi, lo; bsplit(v, hi, lo);
  DH[idx] = hi; DL[idx] = lo;
}

// z0 frags (buf0): [16 grp][8 kt][64][8], z0[h][b] = enc_b[h].   (validated)
__global__ void k_initF(const float* __restrict__ enc_b,
                        u16* __restrict__ ZH, u16* __restrict__ ZL) {
  int idx = blockIdx.x * 256 + threadIdx.x;     // 65536 (grid 256)
  int e = idx & 7, lane = (idx >> 3) & 63;
  int kt = (idx >> 9) & 7;
  int h = kt * 32 + 4 * (lane >> 4) + (e & 3) + 16 * (e >> 2);
  float v = enc_b[h];
  u16 hi, lo; bsplit(v, hi, lo);
  ZH[idx] = hi; ZL[idx] = lo;
}

// zM[grp][rank][h_loc][b] = enc_b[rank*16 + h_loc]
__global__ void k_zm0(const float* __restrict__ enc_b, float* __restrict__ zM) {
  int idx = blockIdx.x * 256 + threadIdx.x;     // 65536 (grid 256)
  zM[idx] = enc_b[(idx >> 4) & 255];
}

// ---------------------------------------------------------------------------
// One substep, 512-thread blocks (8 waves = 2/SIMD for latency hiding).
// 256 blocks = 16 groups (16 b) x 16 ranks (16 h); coherence = dispatch edge.
// Wave wq: phase A computes ho tiles {2wq, 2wq+1} -> exactly its kt2=wq hdn
// B-frag (register repack); phase B owns h-pair [2wq, 2wq+2) = cols
// [40wq, 40wq+40) via W2 tiles m0..m0+2 (m0 = (5wq)>>1), per-quad ownership
// guard. LDS padded >80KB to pin 1 block/CU (per-XCD W2 footprint constant).
__global__ __launch_bounds__(512, 1)
void k_step(char* __restrict__ wsb, const float* __restrict__ f_b1,
            const float* __restrict__ f_b2, const float* __restrict__ dec_b,
            float* __restrict__ out, int sub) {
  const int tid = threadIdx.x, lane = tid & 63, wq = tid >> 6;   // wq 0..7
  const int grp = blockIdx.x >> 4, rank = blockIdx.x & 15;
  const int gg = lane >> 4, c16 = lane & 15;

  if (sub == NSUB && rank != 0) return;         // final launch: decode only

  // LDS: zs hi/lo 16K | hx hi/lo 16K | red 7K | b1L 1K | b2L 1.25K | pad->84K
  __shared__ __align__(16) char smem[84096];
  u16* zsH = (u16*)smem;                        // 8 KB
  u16* zsL = (u16*)(smem + 8192);
  u16* hxH = (u16*)(smem + 16384);              // 8 KB
  u16* hxL = (u16*)(smem + 24576);
  f32x4* red4 = (f32x4*)(smem + 32768);         // 7 KB (7 x 64 x 16B)
  float* b1L  = (float*)(smem + 40960);         // 256 f32
  float* b2L  = (float*)(smem + 41984);         // 320 f32

  if (tid < 256) b1L[tid] = f_b1[tid];
  for (int i = tid; i < 320; i += 512) {
    int hl = i / 20, c = i - hl * 20;
    b2L[i] = (c < C_) ? f_b2[(rank * 16 + hl) * C_ + c] : 0.f;
  }

  const bf16x8* W2Hg = (const bf16x8*)(wsb + OFF_W2H);
  const bf16x8* W2Lg = (const bf16x8*)(wsb + OFF_W2L);
  const bf16x8* W1Hg = (const bf16x8*)(wsb + OFF_W1H);
  const bf16x8* W1Lg = (const bf16x8*)(wsb + OFF_W1L);
  const bf16x8* DHg  = (const bf16x8*)(wsb + OFF_DEH);
  const bf16x8* DLg  = (const bf16x8*)(wsb + OFF_DEL);
  const float*  dXr  = (const float*)(wsb + OFF_DXR);
  float* zM = (float*)(wsb + OFF_ZM) + ((size_t)(grp * 16 + rank)) * 256;

  // fp32 master z: wave wq owns h-pair {2wq, 2wq+1}, lane c16 = b
  float zm[2];
  zm[0] = zM[(2 * wq + 0) * 16 + c16];
  zm[1] = zM[(2 * wq + 1) * 16 + c16];

  // ---- stage this group's z frags (hi+lo) into LDS ----
  {
    const f32x4* gzH = (const f32x4*)(wsb + OFF_ZFH +
                         ((size_t)(sub & 1) * NGRP + grp) * 8192);
    const f32x4* gzL = (const f32x4*)(wsb + OFF_ZFL +
                         ((size_t)(sub & 1) * NGRP + grp) * 8192);
    ((f32x4*)zsH)[tid] = gzH[tid];
    ((f32x4*)zsL)[tid] = gzL[tid];
  }
  __syncthreads();

  // ---- decode (even subs, rank 0): out[sub/2] = z @ decW + dec_b ----
  // kt-split over all 8 waves (kt = wq), 7 partials through LDS.
  if (((sub & 1) == 0) && rank == 0) {
    f32x4 ad = (f32x4){0.f, 0.f, 0.f, 0.f};
    {
      bf16x8 dh = DHg[wq * 64 + lane], dl = DLg[wq * 64 + lane];
      bf16x8 zh = ((const bf16x8*)zsH)[wq * 64 + lane];
      bf16x8 zl = ((const bf16x8*)zsL)[wq * 64 + lane];
      ad = __builtin_amdgcn_mfma_f32_16x16x32_bf16(dh, zh, ad, 0, 0, 0);
      ad = __builtin_amdgcn_mfma_f32_16x16x32_bf16(dh, zl, ad, 0, 0, 0);
      ad = __builtin_amdgcn_mfma_f32_16x16x32_bf16(dl, zh, ad, 0, 0, 0);
    }
    if (wq) red4[(wq - 1) * 64 + lane] = ad;
    __syncthreads();
    if (wq == 0) {
      #pragma unroll
      for (int q = 0; q < 7; ++q) ad += red4[q * 64 + lane];
      float4 q0;
      q0.x = ad[0] + dec_b[4 * gg + 0]; q0.y = ad[1] + dec_b[4 * gg + 1];
      q0.z = ad[2] + dec_b[4 * gg + 2]; q0.w = ad[3] + dec_b[4 * gg + 3];
      *(float4*)(out + (size_t)(sub >> 1) * 4096 +
                 (grp * 16 + c16) * 16 + 4 * gg) = q0;
    }
    __syncthreads();
  }
  if (sub == NSUB) return;

  // ---- phase A: wave wq computes ho tiles mtg = 2wq, 2wq+1 ----
  f32x4 aa[2];
  aa[0] = (f32x4){0.f, 0.f, 0.f, 0.f};
  aa[1] = (f32x4){0.f, 0.f, 0.f, 0.f};
  #pragma unroll
  for (int kt = 0; kt < 8; ++kt) {
    bf16x8 zh = ((const bf16x8*)zsH)[kt * 64 + lane];
    bf16x8 zl = ((const bf16x8*)zsL)[kt * 64 + lane];
    #pragma unroll
    for (int mm = 0; mm < 2; ++mm) {
      int mtg = 2 * wq + mm;
      bf16x8 wh = W1Hg[(mtg * 8 + kt) * 64 + lane];
      bf16x8 wl = W1Lg[(mtg * 8 + kt) * 64 + lane];
      aa[mm] = __builtin_amdgcn_mfma_f32_16x16x32_bf16(wh, zh, aa[mm], 0, 0, 0);
      aa[mm] = __builtin_amdgcn_mfma_f32_16x16x32_bf16(wh, zl, aa[mm], 0, 0, 0);
      aa[mm] = __builtin_amdgcn_mfma_f32_16x16x32_bf16(wl, zh, aa[mm], 0, 0, 0);
    }
  }

  // ---- register repack: C(mm) -> this wave's kt2 = wq B-frag (e = r+4mm) ---
  {
    bf16x8 hH, hL;
    #pragma unroll
    for (int mm = 0; mm < 2; ++mm)
      #pragma unroll
      for (int r = 0; r < 4; ++r) {
        float v = aa[mm][r] + b1L[(2 * wq + mm) * 16 + 4 * gg + r];
        v = fmaxf(v, 0.f);
        u16 hi, lo; bsplit(v, hi, lo);
        hH[r + 4 * mm] = (short)hi;
        hL[r + 4 * mm] = (short)lo;
      }
    ((bf16x8*)hxH)[wq * 64 + lane] = hH;
    ((bf16x8*)hxL)[wq * 64 + lane] = hL;
  }
  __syncthreads();

  // ---- phase B: wave wq computes W2 tiles m0..m0+2, full K=256 ----
  const int m0 = (5 * wq) >> 1;                 // 0,2,5,7,10,12,15,17
  f32x4 ab[3];
  #pragma unroll
  for (int ml = 0; ml < 3; ++ml) ab[ml] = (f32x4){0.f, 0.f, 0.f, 0.f};
  #pragma unroll
  for (int kt = 0; kt < 8; ++kt) {
    bf16x8 hh = ((const bf16x8*)hxH)[kt * 64 + lane];
    bf16x8 hl = ((const bf16x8*)hxL)[kt * 64 + lane];
    #pragma unroll
    for (int ml = 0; ml < 3; ++ml) {
      bf16x8 wh = W2Hg[(((rank * 20 + m0 + ml) * 8) + kt) * 64 + lane];
      bf16x8 wl = W2Lg[(((rank * 20 + m0 + ml) * 8) + kt) * 64 + lane];
      ab[ml] = __builtin_amdgcn_mfma_f32_16x16x32_bf16(wh, hh, ab[ml], 0, 0, 0);
      ab[ml] = __builtin_amdgcn_mfma_f32_16x16x32_bf16(wh, hl, ab[ml], 0, 0, 0);
      ab[ml] = __builtin_amdgcn_mfma_f32_16x16x32_bf16(wl, hh, ab[ml], 0, 0, 0);
    }
  }

  // ---- epilogue: ownership-guarded tanh/contract; z update; frag store ----
  {
    float ph[2] = {0.f, 0.f};
    #pragma unroll
    for (int ml = 0; ml < 3; ++ml) {
      int col0 = (m0 + ml) * 16 + 4 * gg;
      int hl_  = col0 / 20;                     // 20-pad: quad never crosses h
      if ((hl_ >> 1) == wq) {                   // this wave owns h-pair
        int c0 = col0 - hl_ * 20;
        float4 b2v = *(const float4*)&b2L[col0];
        float4 dxv = *(const float4*)(dXr +
            ((size_t)sub * 256 + grp * 16 + c16) * 20 + c0);
        float t0 = fast_tanh(ab[ml][0] + b2v.x);
        float t1 = fast_tanh(ab[ml][1] + b2v.y);
        float t2 = fast_tanh(ab[ml][2] + b2v.z);
        float t3 = fast_tanh(ab[ml][3] + b2v.w);
        float contrib = fmaf(t0, dxv.x, fmaf(t1, dxv.y, fmaf(t2, dxv.z, t3 * dxv.w)));
        ph[hl_ & 1] += contrib;
      }
    }
    #pragma unroll
    for (int hh = 0; hh < 2; ++hh) {
      float v = ph[hh];
      v += __shfl_xor(v, 16);                   // sum the 4 gg groups
      v += __shfl_xor(v, 32);
      zm[hh] += v;
    }
    if (gg == 0) {
      // zM master store (2 h per wave)
      zM[(2 * wq + 0) * 16 + c16] = zm[0];
      zM[(2 * wq + 1) * 16 + c16] = zm[1];
      // zF frag ushort2 store; hg = rank*16 + 2wq + hh (bijection verified)
      int ktf = rank >> 1;
      int lp  = c16 + 16 * (wq >> 1);
      int e0  = ((2 * wq) & 3) + 4 * (rank & 1);
      int fi  = (ktf * 64 + lp) * 8 + e0;       // u16 units, fi even
      u16* zdH = (u16*)(wsb + OFF_ZFH) +
                 ((size_t)((sub + 1) & 1) * NGRP + grp) * 4096;
      u16* zdL = (u16*)(wsb + OFF_ZFL) +
                 ((size_t)((sub + 1) & 1) * NGRP + grp) * 4096;
      ushort2 vh, vl;
      u16 h0, l0;
      bsplit(zm[0], h0, l0); vh.x = h0; vl.x = l0;
      bsplit(zm[1], h0, l0); vh.y = h0; vl.y = l0;
      *(ushort2*)(zdH + fi) = vh;
      *(ushort2*)(zdL + fi) = vl;
    }
  }
}

// ---------------------------------------------------------------------------
extern "C" void kernel_launch(void* const* d_in, const int* in_sizes, int n_in,
                              void* d_out, int out_size, void* d_ws, size_t ws_size,
                              hipStream_t stream) {
  const float* ts    = (const float*)d_in[0];
  const float* us    = (const float*)d_in[1];
  const float* enc_b = (const float*)d_in[5];
  const float* dec_W = (const float*)d_in[6];
  const float* dec_b = (const float*)d_in[7];
  const float* f_W1  = (const float*)d_in[8];
  const float* f_b1  = (const float*)d_in[9];
  const float* f_W2  = (const float*)d_in[10];
  const float* f_b2  = (const float*)d_in[11];
  float* out = (float*)d_out;
  char* wsb = (char*)d_ws;

  k_dx   <<<5080, 256, 0, stream>>>(ts, us, (float*)(wsb + OFF_DXR));
  k_w2f  <<<5120, 256, 0, stream>>>(f_W2, (u16*)(wsb + OFF_W2H), (u16*)(wsb + OFF_W2L));
  k_w1f  <<<256, 256, 0, stream>>>(f_W1, (u16*)(wsb + OFF_W1H), (u16*)(wsb + OFF_W1L));
  k_def  <<<16, 256, 0, stream>>>(dec_W, (u16*)(wsb + OFF_DEH), (u16*)(wsb + OFF_DEL));
  k_initF<<<256, 256, 0, stream>>>(enc_b, (u16*)(wsb + OFF_ZFH), (u16*)(wsb + OFF_ZFL));
  k_zm0  <<<256, 256, 0, stream>>>(enc_b, (float*)(wsb + OFF_ZM));

  for (int sub = 0; sub <= NSUB; ++sub)
    k_step<<<256, 512, 0, stream>>>(wsb, f_b1, f_b2, dec_b, out, sub);
}